// Round 4
// baseline (239.768 us; speedup 1.0000x reference)
//
#include <hip/hip_runtime.h>
#include <stdint.h>

#define B_ 4
#define S_ 4096
#define D_ 1024
#define E_ 2048          // 2*D
#define K_ 1024
#define M_ (B_*S_)       // 16384
#define NCHAIN 32        // 128-row tiles per batch = chain length
#define SENT 0xFFFFFFFFFFFFFFFFull

typedef __bf16 bf16x8 __attribute__((ext_vector_type(8)));
typedef float  f32x4  __attribute__((ext_vector_type(4)));
typedef _Float16 f16x2 __attribute__((ext_vector_type(2)));

__device__ __forceinline__ unsigned short f2bf(float f) {
    union { float f; unsigned int u; } x; x.f = f;
    unsigned int u = x.u;
    return (unsigned short)((u + 0x7fffu + ((u >> 16) & 1u)) >> 16);
}

__device__ __forceinline__ void gload16(const void* g, void* l) {
    __builtin_amdgcn_global_load_lds(
        (const __attribute__((address_space(1))) void*)(uintptr_t)g,
        (__attribute__((address_space(3))) void*)(uintptr_t)l,
        16, 0, 0);
}

// RNE f32->bf16 pair pack (compiler emits packed cvt; same rounding as f2bf)
__device__ __forceinline__ unsigned int cvtpk2(float lo, float hi) {
    union { __bf16 h[2]; unsigned int u; } r;
    r.h[0] = (__bf16)lo; r.h[1] = (__bf16)hi;
    return r.u;
}
__device__ __forceinline__ uint4 cvt8(float4 a, float4 b) {
    uint4 q;
    q.x = cvtpk2(a.x, a.y); q.y = cvtpk2(a.z, a.w);
    q.z = cvtpk2(b.x, b.y); q.w = cvtpk2(b.z, b.w);
    return q;
}

// pack (c = sigmoid(-gate), v = sigmoid(gate)*g(hidden)) as half2 in a uint
__device__ __forceinline__ unsigned int packCV(float hid, float gat) {
    float e  = __expf(gat);
    float c  = __builtin_amdgcn_rcpf(1.f + e);          // sigmoid(-gate)
    float gg = (hid >= 0.f) ? (hid + 0.5f)
                            : __builtin_amdgcn_rcpf(1.f + __expf(-hid));
    float v  = (1.f - c) * gg;                           // sigmoid(gate)*g(hidden)
    union { f16x2 h; unsigned int u; } pk;
    pk.h[0] = (_Float16)c; pk.h[1] = (_Float16)v;
    return pk.u;
}

// ---------------- W interleave->bf16 + sentinel init (x pre-pass DELETED) -----
// blocks [0,256): W interleave (8 float4/thread); [256,320): segAgg sentinels.
__global__ __launch_bounds__(256)
void wcvt(const float* __restrict__ w, unsigned short* __restrict__ wb,
          unsigned long long* __restrict__ segAgg) {
    const int b = blockIdx.x;
    const int t = threadIdx.x;
    if (b < 256) {
        // W: 524,288 float4 total; 2048 per block; 8 per thread
        const int base4 = b * 2048 + t;             // float4 index into [E_,K_]
        float4 f[8];
        const float* srcs[8];
#pragma unroll
        for (int k = 0; k < 8; k++) {
            int i = (base4 + k * 256) * 4;
            int r = i >> 10;            // row in interleaved [E_, K_]
            int kk = i & 1023;
            int d = r >> 1, g = r & 1;
            srcs[k] = w + (size_t)(g * D_ + d) * K_ + kk;
        }
#pragma unroll
        for (int k = 0; k < 8; k++) f[k] = *(const float4*)srcs[k];
#pragma unroll
        for (int k = 0; k < 8; k++) {
            int i = (base4 + k * 256) * 4;
            ushort4 o;
            o.x = f2bf(f[k].x); o.y = f2bf(f[k].y);
            o.z = f2bf(f[k].z); o.w = f2bf(f[k].w);
            *(ushort4*)(wb + i) = o;
        }
    } else {
        // sentinel: 131072 u64 = 64 blocks * 256 threads * 8
        const size_t base = (size_t)(b - 256) * 2048 + t;
#pragma unroll
        for (int k = 0; k < 8; k++) segAgg[base + (size_t)k * 256] = SENT;
    }
}

// ---------------- GEMM (fp32 A, in-loop cvt) + activation + scan/apply --------
#define BM 128
#define BN 128
#define BK 32

// 3 blocks/CU: regs ~84+64acc < 512/3; LDS 3x52KB = 156 <= 160KB.
__global__ __launch_bounds__(256, 3)
void gemm_fused(const float* __restrict__ x,
                const unsigned short* __restrict__ wb,
                unsigned long long* __restrict__ segAgg,
                float* __restrict__ out) {
    __shared__ unsigned short As[BM * BK];                 // 8 KB
    __shared__ unsigned short Bs[BN * BK];                 // 8 KB
    __shared__ __align__(16) unsigned int Ep[4][64][36];   // 36 KB (pad 32->36)

    // ord = s*64 + (eB*4 + bat): chain position s SLOWEST (lookback-safe,
    // predecessors in earlier scheduling rounds). XCD j=ord%8 gets bat=j&3 and
    // 8 eB panels of parity j>>2 -> 2MB wb L2-resident; x slice on 2 XCDs.
    const int ord   = blockIdx.x;       // 0..2047
    const int inner = ord & 63;
    const int eB    = inner >> 2;       // 0..15
    const int bat   = inner & 3;        // 0..3
    const int sIx   = ord >> 6;         // 0..31 chain position within batch
    const int mB    = bat * NCHAIN + sIx;
    const int mBase = mB * BM;
    const int eBase = eB * BN;

    const int tid  = threadIdx.x;
    const int lane = tid & 63;
    const int w    = tid >> 6;
    const int waveM = (w >> 1) * 64;
    const int waveN = (w & 1) * 64;

    f32x4 acc[4][4] = {};

    // staging: lane tid covers (row = tid>>2, 32B fp32 chunk = tid&3)
    const int row0 = tid >> 2, cu = tid & 3;
    const float* aF0 = x + (size_t)(mBase + row0) * K_ + cu * 8;   // fp32 A
    const float* aF1 = aF0 + (size_t)64 * K_;
    const unsigned short* bG0 = wb + (size_t)(eBase + row0) * K_ + cu * 8;
    const unsigned short* bG1 = bG0 + (size_t)64 * K_;
    // wave-uniform LDS bases for B (HW adds lane*16B)
    unsigned short* bL0 = Bs + (size_t)(w * 64) * 8;
    unsigned short* bL1 = Bs + (size_t)(256 + w * 64) * 8;

    const int mrow = lane & 15;
    const int kg   = (lane >> 4) * 8;

    for (int k0 = 0; k0 < K_; k0 += BK) {
        // issue fp32 A loads at loop top: their drain overlaps barrier entry
        float4 a0 = *(const float4*)(aF0 + k0);
        float4 a1 = *(const float4*)(aF0 + k0 + 4);
        float4 a2 = *(const float4*)(aF1 + k0);
        float4 a3 = *(const float4*)(aF1 + k0 + 4);
        __syncthreads();
        gload16(bG0 + k0, bL0);
        gload16(bG1 + k0, bL1);
        // cvt in regs -> linear conflict-free ds_write_b128 (addr = tid*16B)
        *(uint4*)(As + (size_t)tid * 8)        = cvt8(a0, a1);
        *(uint4*)(As + 2048 + (size_t)tid * 8) = cvt8(a2, a3);
        __syncthreads();

        bf16x8 af[4], bfr[4];
#pragma unroll
        for (int i = 0; i < 4; i++)
            af[i] = *(const bf16x8*)(As + (size_t)(waveM + i * 16 + mrow) * BK + kg);
#pragma unroll
        for (int j = 0; j < 4; j++)
            bfr[j] = *(const bf16x8*)(Bs + (size_t)(waveN + j * 16 + mrow) * BK + kg);
#pragma unroll
        for (int i = 0; i < 4; i++)
#pragma unroll
            for (int j = 0; j < 4; j++)
                acc[i][j] = __builtin_amdgcn_mfma_f32_16x16x32_bf16(af[i], bfr[j], acc[i][j], 0, 0, 0);
    }

    // ---- epilogue 1: activation + pack + LDS transpose ----
    const int q    = lane >> 4;
    const int odd  = lane & 1;
    const int colL = (lane & 15) >> 1;            // 0..7
    unsigned int* EpW = &Ep[w][0][0];

#pragma unroll
    for (int i = 0; i < 4; i++) {
#pragma unroll
        for (int j = 0; j < 4; j++) {
            float o0 = __shfl_xor(acc[i][j][0], 1, 64);
            float o1 = __shfl_xor(acc[i][j][1], 1, 64);
            float o2 = __shfl_xor(acc[i][j][2], 1, 64);
            float o3 = __shfl_xor(acc[i][j][3], 1, 64);
            float m0 = odd ? acc[i][j][2] : acc[i][j][0];
            float m1 = odd ? acc[i][j][3] : acc[i][j][1];
            float p0 = odd ? o2 : o0;
            float p1 = odd ? o3 : o1;
            float h0 = odd ? p0 : m0, g0 = odd ? m0 : p0;
            float h1 = odd ? p1 : m1, g1 = odd ? m1 : p1;
            int row = i * 16 + q * 4 + odd * 2;
            int col = j * 8 + colL;
            EpW[(row    ) * 36 + col] = packCV(h0, g0);
            EpW[(row + 1) * 36 + col] = packCV(h1, g1);
        }
    }

    // ---- epilogue 2: quarter reduce (32 rows x 64 ch per thread-group) ----
    __syncthreads();                      // Ep fully written; As/Bs dead -> reuse
    float* scratch = (float*)As;          // [4][64][2] floats = 2 KB
    float* hpre    = scratch + 512;       // 64 floats

    const int dl = tid & 63;              // channel 0..63 within block
    const int qt = tid >> 6;              // quarter 0..3 (rows qt*32 .. +31)
    const int wq = (qt >> 1) * 2 + (dl >> 5);
    const int rB = (qt & 1) * 32;
    const int cc_ = dl & 31;
    const unsigned int* src = &Ep[wq][rB][cc_];
    {
        float C = 1.f, V = 0.f;
#pragma unroll 8
        for (int rr = 0; rr < 32; rr++) {
            union { unsigned int u; f16x2 h; } uu;
            uu.u = src[rr * 36];
            float cv_c = (float)uu.h[0], cv_v = (float)uu.h[1];
            V = fmaf(cv_c, V, cv_v);
            C *= cv_c;
        }
        scratch[(qt * 64 + dl) * 2 + 0] = C;
        scratch[(qt * 64 + dl) * 2 + 1] = V;
    }
    __syncthreads();

    // ---- epilogue 3 (wave 0 only): publish aggregate, then lookback ----
    // Relaxed agent-scope 8B atomic publish: payload IS the data
    // (sentinel-validated); no fence (fence caused L2 inv, round 2).
    if (tid < 64) {
        float C0 = scratch[(0 * 64 + tid) * 2], V0 = scratch[(0 * 64 + tid) * 2 + 1];
        float C1 = scratch[(1 * 64 + tid) * 2], V1 = scratch[(1 * 64 + tid) * 2 + 1];
        float C2 = scratch[(2 * 64 + tid) * 2], V2 = scratch[(2 * 64 + tid) * 2 + 1];
        float C3 = scratch[(3 * 64 + tid) * 2], V3 = scratch[(3 * 64 + tid) * 2 + 1];
        float Cb = (C0 * C1) * (C2 * C3);
        float Vb = fmaf(C3, fmaf(C2, fmaf(C1, V0, V1), V2), V3);
        union { unsigned long long u; float f[2]; } pk;
        pk.f[0] = Cb; pk.f[1] = Vb;
        // UNCONDITIONAL publish before any wait -> no deadlock possible.
        __hip_atomic_store(&segAgg[(size_t)ord * 64 + tid], pk.u,
                           __ATOMIC_RELAXED, __HIP_MEMORY_SCOPE_AGENT);

        // aggregate-only lookback: fold predecessors t = 0..sIx-1 in order.
        float h = 0.f;
        const size_t chanB = (size_t)inner * 64 + tid;  // (eB*4+bat)*64+ch
#pragma unroll 1
        for (int t0 = 0; t0 < NCHAIN; t0 += 8) {
            if (t0 >= sIx) break;
            unsigned long long vb[8];
#pragma unroll
            for (int k = 0; k < 8; k++)
                vb[k] = (t0 + k < sIx)
                    ? __hip_atomic_load(&segAgg[(size_t)(t0 + k) * 4096 + chanB],
                                        __ATOMIC_RELAXED, __HIP_MEMORY_SCOPE_AGENT)
                    : 0x3f800000ull;    // identity (C=1, V=0)
#pragma unroll
            for (int k = 0; k < 8; k++) {
                if (t0 + k < sIx) {
                    while (vb[k] == SENT)
                        vb[k] = __hip_atomic_load(&segAgg[(size_t)(t0 + k) * 4096 + chanB],
                                                  __ATOMIC_RELAXED, __HIP_MEMORY_SCOPE_AGENT);
                }
            }
#pragma unroll
            for (int k = 0; k < 8; k++) {
                union { unsigned long long u; float f[2]; } qd; qd.u = vb[k];
                h = fmaf(qd.f[0], h, qd.f[1]);
            }
        }
        hpre[tid] = h;
    }
    __syncthreads();

    // ---- epilogue 4: apply h_t = c_t*h_{t-1} + v_t, write out (fp32) ----
    {
        float h = hpre[dl];
        if (qt > 0) h = fmaf(scratch[(0 * 64 + dl) * 2], h, scratch[(0 * 64 + dl) * 2 + 1]);
        if (qt > 1) h = fmaf(scratch[(1 * 64 + dl) * 2], h, scratch[(1 * 64 + dl) * 2 + 1]);
        if (qt > 2) h = fmaf(scratch[(2 * 64 + dl) * 2], h, scratch[(2 * 64 + dl) * 2 + 1]);
        float* outp = out + (size_t)(mBase + qt * 32) * D_ + (eB * 64 + dl);
#pragma unroll 8
        for (int rr = 0; rr < 32; rr++) {
            union { unsigned int u; f16x2 hh; } uu;
            uu.u = src[rr * 36];
            h = fmaf((float)uu.hh[0], h, (float)uu.hh[1]);
            outp[(size_t)rr * D_] = h;
        }
    }
}

// ---------------- launch ----------------
extern "C" void kernel_launch(void* const* d_in, const int* in_sizes, int n_in,
                              void* d_out, int out_size, void* d_ws, size_t ws_size,
                              hipStream_t stream) {
    const float* x = (const float*)d_in[0];
    const float* wmat = (const float*)d_in[1];
    float* out = (float*)d_out;
    char* ws = (char*)d_ws;

    unsigned short* wb = (unsigned short*)(ws);                       // 4 MB @ 0
    unsigned long long* segAgg = (unsigned long long*)(ws + (4u << 20)); // 1 MB @ 4M

    wcvt<<<320, 256, 0, stream>>>(wmat, wb, segAgg);
    gemm_fused<<<2048, 256, 0, stream>>>(x, wb, segAgg, out);
}

// Round 6
// 210.016 us; speedup vs baseline: 1.1417x; 1.1417x over previous
//
#include <hip/hip_runtime.h>
#include <stdint.h>

#define B_ 4
#define S_ 4096
#define D_ 1024
#define E_ 2048          // 2*D
#define K_ 1024
#define M_ (B_*S_)       // 16384
#define NCHAIN 32        // 128-row tiles per batch = chain length
#define SENT 0xFFFFFFFFFFFFFFFFull

typedef __bf16 bf16x8 __attribute__((ext_vector_type(8)));
typedef float  f32x4  __attribute__((ext_vector_type(4)));
typedef _Float16 f16x2 __attribute__((ext_vector_type(2)));

__device__ __forceinline__ unsigned short f2bf(float f) {
    union { float f; unsigned int u; } x; x.f = f;
    unsigned int u = x.u;
    return (unsigned short)((u + 0x7fffu + ((u >> 16) & 1u)) >> 16);
}

__device__ __forceinline__ void gload16(const void* g, void* l) {
    __builtin_amdgcn_global_load_lds(
        (const __attribute__((address_space(1))) void*)(uintptr_t)g,
        (__attribute__((address_space(3))) void*)(uintptr_t)l,
        16, 0, 0);
}

// pack (c = sigmoid(-gate), v = sigmoid(gate)*g(hidden)) as half2 in a uint
__device__ __forceinline__ unsigned int packCV(float hid, float gat) {
    float e  = __expf(gat);
    float c  = __builtin_amdgcn_rcpf(1.f + e);          // sigmoid(-gate)
    float gg = (hid >= 0.f) ? (hid + 0.5f)
                            : __builtin_amdgcn_rcpf(1.f + __expf(-hid));
    float v  = (1.f - c) * gg;                           // sigmoid(gate)*g(hidden)
    union { f16x2 h; unsigned int u; } pk;
    pk.h[0] = (_Float16)c; pk.h[1] = (_Float16)v;
    return pk.u;
}

// ---------------- conversion + lookback-state init (grid-strided, 8x ILP) -----
// blocks [0,2048): x -> bf16 (8 float4/thread)
// blocks [2048,2304): W interleave -> bf16 (8 float4/thread)
// blocks [2304,2368): segAgg sentinel init (8 u64/thread)
__global__ __launch_bounds__(256)
void cvt_xw(const float* __restrict__ x, unsigned short* __restrict__ xb,
            const float* __restrict__ w, unsigned short* __restrict__ wb,
            unsigned long long* __restrict__ segAgg) {
    const int b = blockIdx.x;
    const int t = threadIdx.x;
    if (b < 2048) {
        // x: 4,194,304 float4 total; 2048 per block; 8 per thread (indep chains)
        const float4* xp = (const float4*)x + (size_t)b * 2048 + t;
        ushort4*      op = (ushort4*)xb + (size_t)b * 2048 + t;
        float4 f[8];
#pragma unroll
        for (int k = 0; k < 8; k++) f[k] = xp[(size_t)k * 256];
#pragma unroll
        for (int k = 0; k < 8; k++) {
            ushort4 o;
            o.x = f2bf(f[k].x); o.y = f2bf(f[k].y);
            o.z = f2bf(f[k].z); o.w = f2bf(f[k].w);
            op[(size_t)k * 256] = o;
        }
    } else if (b < 2304) {
        // W: 524,288 float4 total; 2048 per block; 8 per thread
        const int base4 = (b - 2048) * 2048 + t;    // float4 index into [E_,K_]
        float4 f[8];
        const float* srcs[8];
#pragma unroll
        for (int k = 0; k < 8; k++) {
            int i = (base4 + k * 256) * 4;
            int r = i >> 10;            // row in interleaved [E_, K_]
            int kk = i & 1023;
            int d = r >> 1, g = r & 1;
            srcs[k] = w + (size_t)(g * D_ + d) * K_ + kk;
        }
#pragma unroll
        for (int k = 0; k < 8; k++) f[k] = *(const float4*)srcs[k];
#pragma unroll
        for (int k = 0; k < 8; k++) {
            int i = (base4 + k * 256) * 4;
            ushort4 o;
            o.x = f2bf(f[k].x); o.y = f2bf(f[k].y);
            o.z = f2bf(f[k].z); o.w = f2bf(f[k].w);
            *(ushort4*)(wb + i) = o;
        }
    } else {
        // sentinel: 131072 u64 = 64 blocks * 256 threads * 8
        const size_t base = (size_t)(b - 2304) * 2048 + t;
#pragma unroll
        for (int k = 0; k < 8; k++) segAgg[base + (size_t)k * 256] = SENT;
    }
}

// ---------------- GEMM + activation + in-block scan/apply (decoupled lookback) --
#define BM 128
#define BN 128
#define BK 32

// 3 blocks/CU: regs 68+64acc=132 (3x132=396<=512/SIMD), LDS 3x52KB=156<=160KB.
__global__ __launch_bounds__(256, 3)
void gemm_fused(const unsigned short* __restrict__ xb,
                const unsigned short* __restrict__ wb,
                unsigned long long* __restrict__ segAgg,
                float* __restrict__ out) {
    __shared__ unsigned short As[BM * BK];                 // 8 KB
    __shared__ unsigned short Bs[BN * BK];                 // 8 KB
    __shared__ __align__(16) unsigned int Ep[4][64][36];   // 36 KB (pad 32->36)

    // ord = s*64 + (eB*4 + bat): chain position s SLOWEST (lookback-safe,
    // predecessors in earlier scheduling rounds). XCD j (= ord%8) gets bat=j&3
    // and the 8 eB panels of parity j>>2 -> 2MB wb L2-resident; one 256KB xb
    // slice per round shared with one other XCD.
    const int ord   = blockIdx.x;       // 0..2047
    const int inner = ord & 63;
    const int eB    = inner >> 2;       // 0..15
    const int bat   = inner & 3;        // 0..3
    const int sIx   = ord >> 6;         // 0..31 chain position within batch
    const int mB    = bat * NCHAIN + sIx;
    const int mBase = mB * BM;
    const int eBase = eB * BN;

    const int tid  = threadIdx.x;
    const int lane = tid & 63;
    const int w    = tid >> 6;
    const int waveM = (w >> 1) * 64;
    const int waveN = (w & 1) * 64;

    f32x4 acc[4][4] = {};

    // staging: lane tid covers (row = tid>>2, 16B chunk = tid&3)
    const int row0 = tid >> 2, cu = tid & 3;
    const unsigned short* aG0 = xb + (size_t)(mBase + row0) * K_ + cu * 8;
    const unsigned short* aG1 = aG0 + (size_t)64 * K_;
    const unsigned short* bG0 = wb + (size_t)(eBase + row0) * K_ + cu * 8;
    const unsigned short* bG1 = bG0 + (size_t)64 * K_;
    // wave-uniform LDS bases (HW adds lane*16B)
    unsigned short* aL0 = As + (size_t)(w * 64) * 8;
    unsigned short* aL1 = As + (size_t)(256 + w * 64) * 8;
    unsigned short* bL0 = Bs + (size_t)(w * 64) * 8;
    unsigned short* bL1 = Bs + (size_t)(256 + w * 64) * 8;

    const int mrow = lane & 15;
    const int kg   = (lane >> 4) * 8;

    // ---- K-loop: minimum 2-phase. Per iter: frags->regs, barrier (LDS
    // free), ISSUE next-tile gload_lds, MFMA overlaps the loads in flight,
    // vmcnt(0)+barrier. (Round-3 schedule exposed full load latency between
    // back-to-back barriers with no intra-block overlap: MfmaUtil 25%.)
    // Safety: __syncthreads on gfx950 = s_waitcnt vmcnt(0) lgkmcnt(0) +
    // s_barrier, so frag ds_reads complete before any wave's gload16
    // overwrites LDS, and staged tiles land before the next ds_read.
    gload16(aG0, aL0);
    gload16(aG1, aL1);
    gload16(bG0, bL0);
    gload16(bG1, bL1);
    __syncthreads();                       // tile 0 staged (vmcnt0 + barrier)

    for (int k0 = 0; k0 < K_; k0 += BK) {
        bf16x8 af[4], bfr[4];
#pragma unroll
        for (int i = 0; i < 4; i++)
            af[i] = *(const bf16x8*)(As + (size_t)(waveM + i * 16 + mrow) * BK + kg);
#pragma unroll
        for (int j = 0; j < 4; j++)
            bfr[j] = *(const bf16x8*)(Bs + (size_t)(waveN + j * 16 + mrow) * BK + kg);
        __syncthreads();                   // frags in regs (lgkmcnt0); LDS dead

        const int kn = k0 + BK;
        if (kn < K_) {                     // issue next tile: flies under MFMA
            gload16(aG0 + kn, aL0);
            gload16(aG1 + kn, aL1);
            gload16(bG0 + kn, bL0);
            gload16(bG1 + kn, bL1);
        }
        __builtin_amdgcn_sched_barrier(0); // pin stage-issue above MFMA cluster

#pragma unroll
        for (int i = 0; i < 4; i++)
#pragma unroll
            for (int j = 0; j < 4; j++)
                acc[i][j] = __builtin_amdgcn_mfma_f32_16x16x32_bf16(af[i], bfr[j], acc[i][j], 0, 0, 0);

        __syncthreads();                   // vmcnt(0): next tile landed
    }

    // ---- epilogue 1: activation + pack + LDS transpose ----
    const int q    = lane >> 4;
    const int odd  = lane & 1;
    const int colL = (lane & 15) >> 1;            // 0..7
    unsigned int* EpW = &Ep[w][0][0];

#pragma unroll
    for (int i = 0; i < 4; i++) {
#pragma unroll
        for (int j = 0; j < 4; j++) {
            float o0 = __shfl_xor(acc[i][j][0], 1, 64);
            float o1 = __shfl_xor(acc[i][j][1], 1, 64);
            float o2 = __shfl_xor(acc[i][j][2], 1, 64);
            float o3 = __shfl_xor(acc[i][j][3], 1, 64);
            float m0 = odd ? acc[i][j][2] : acc[i][j][0];
            float m1 = odd ? acc[i][j][3] : acc[i][j][1];
            float p0 = odd ? o2 : o0;
            float p1 = odd ? o3 : o1;
            float h0 = odd ? p0 : m0, g0 = odd ? m0 : p0;
            float h1 = odd ? p1 : m1, g1 = odd ? m1 : p1;
            int row = i * 16 + q * 4 + odd * 2;
            int col = j * 8 + colL;
            EpW[(row    ) * 36 + col] = packCV(h0, g0);
            EpW[(row + 1) * 36 + col] = packCV(h1, g1);
        }
    }

    // ---- epilogue 2: quarter reduce (32 rows x 64 ch per thread-group) ----
    __syncthreads();                      // Ep fully written; As/Bs dead -> reuse
    float* scratch = (float*)As;          // [4][64][2] floats = 2 KB
    float* hpre    = scratch + 512;       // 64 floats

    const int dl = tid & 63;              // channel 0..63 within block
    const int qt = tid >> 6;              // quarter 0..3 (rows qt*32 .. +31)
    const int wq = (qt >> 1) * 2 + (dl >> 5);
    const int rB = (qt & 1) * 32;
    const int cc_ = dl & 31;
    const unsigned int* src = &Ep[wq][rB][cc_];
    {
        float C = 1.f, V = 0.f;
#pragma unroll 8
        for (int rr = 0; rr < 32; rr++) {
            union { unsigned int u; f16x2 h; } uu;
            uu.u = src[rr * 36];
            float cv_c = (float)uu.h[0], cv_v = (float)uu.h[1];
            V = fmaf(cv_c, V, cv_v);
            C *= cv_c;
        }
        scratch[(qt * 64 + dl) * 2 + 0] = C;
        scratch[(qt * 64 + dl) * 2 + 1] = V;
    }
    __syncthreads();

    // ---- epilogue 3 (wave 0 only): publish aggregate, then lookback ----
    // Relaxed agent-scope 8B atomic publish: the payload IS the data
    // (sentinel-validated); no fence (round-2's fence caused L2 inv: -35us).
    if (tid < 64) {
        float C0 = scratch[(0 * 64 + tid) * 2], V0 = scratch[(0 * 64 + tid) * 2 + 1];
        float C1 = scratch[(1 * 64 + tid) * 2], V1 = scratch[(1 * 64 + tid) * 2 + 1];
        float C2 = scratch[(2 * 64 + tid) * 2], V2 = scratch[(2 * 64 + tid) * 2 + 1];
        float C3 = scratch[(3 * 64 + tid) * 2], V3 = scratch[(3 * 64 + tid) * 2 + 1];
        float Cb = (C0 * C1) * (C2 * C3);
        float Vb = fmaf(C3, fmaf(C2, fmaf(C1, V0, V1), V2), V3);
        union { unsigned long long u; float f[2]; } pk;
        pk.f[0] = Cb; pk.f[1] = Vb;
        // UNCONDITIONAL publish before any wait -> no deadlock possible.
        __hip_atomic_store(&segAgg[(size_t)ord * 64 + tid], pk.u,
                           __ATOMIC_RELAXED, __HIP_MEMORY_SCOPE_AGENT);

        // aggregate-only lookback: fold predecessors t = 0..sIx-1 in order.
        float h = 0.f;
        const size_t chanB = (size_t)inner * 64 + tid;  // (eB*4+bat)*64+ch
#pragma unroll 1
        for (int t0 = 0; t0 < NCHAIN; t0 += 8) {
            if (t0 >= sIx) break;
            unsigned long long vb[8];
#pragma unroll
            for (int k = 0; k < 8; k++)
                vb[k] = (t0 + k < sIx)
                    ? __hip_atomic_load(&segAgg[(size_t)(t0 + k) * 4096 + chanB],
                                        __ATOMIC_RELAXED, __HIP_MEMORY_SCOPE_AGENT)
                    : 0x3f800000ull;    // identity (C=1, V=0)
#pragma unroll
            for (int k = 0; k < 8; k++) {
                if (t0 + k < sIx) {
                    while (vb[k] == SENT)
                        vb[k] = __hip_atomic_load(&segAgg[(size_t)(t0 + k) * 4096 + chanB],
                                                  __ATOMIC_RELAXED, __HIP_MEMORY_SCOPE_AGENT);
                }
            }
#pragma unroll
            for (int k = 0; k < 8; k++) {
                union { unsigned long long u; float f[2]; } qd; qd.u = vb[k];
                h = fmaf(qd.f[0], h, qd.f[1]);
            }
        }
        hpre[tid] = h;
    }
    __syncthreads();

    // ---- epilogue 4: apply h_t = c_t*h_{t-1} + v_t, write out (fp32) ----
    {
        float h = hpre[dl];
        if (qt > 0) h = fmaf(scratch[(0 * 64 + dl) * 2], h, scratch[(0 * 64 + dl) * 2 + 1]);
        if (qt > 1) h = fmaf(scratch[(1 * 64 + dl) * 2], h, scratch[(1 * 64 + dl) * 2 + 1]);
        if (qt > 2) h = fmaf(scratch[(2 * 64 + dl) * 2], h, scratch[(2 * 64 + dl) * 2 + 1]);
        float* outp = out + (size_t)(mBase + qt * 32) * D_ + (eB * 64 + dl);
#pragma unroll 8
        for (int rr = 0; rr < 32; rr++) {
            union { unsigned int u; f16x2 hh; } uu;
            uu.u = src[rr * 36];
            h = fmaf((float)uu.hh[0], h, (float)uu.hh[1]);
            outp[(size_t)rr * D_] = h;
        }
    }
}

// ---------------- launch ----------------
extern "C" void kernel_launch(void* const* d_in, const int* in_sizes, int n_in,
                              void* d_out, int out_size, void* d_ws, size_t ws_size,
                              hipStream_t stream) {
    const float* x = (const float*)d_in[0];
    const float* wmat = (const float*)d_in[1];
    float* out = (float*)d_out;
    char* ws = (char*)d_ws;

    unsigned short* xb = (unsigned short*)(ws);                       // 32 MB @ 0
    unsigned short* wb = (unsigned short*)(ws + (32u << 20));         //  4 MB @ 32M
    unsigned long long* segAgg = (unsigned long long*)(ws + (36u << 20)); // 1 MB @ 36M

    cvt_xw<<<2368, 256, 0, stream>>>(x, xb, wmat, wb, segAgg);
    gemm_fused<<<2048, 256, 0, stream>>>(xb, wb, segAgg, out);
}

// Round 7
// 203.062 us; speedup vs baseline: 1.1808x; 1.0342x over previous
//
#include <hip/hip_runtime.h>
#include <stdint.h>

#define B_ 4
#define S_ 4096
#define D_ 1024
#define E_ 2048          // 2*D
#define K_ 1024
#define M_ (B_*S_)       // 16384
#define NCHAIN 32        // 128-row tiles per batch = chain length
#define SENT 0xFFFFFFFFFFFFFFFFull

typedef __bf16 bf16x8 __attribute__((ext_vector_type(8)));
typedef float  f32x4  __attribute__((ext_vector_type(4)));
typedef _Float16 f16x2 __attribute__((ext_vector_type(2)));

#define BM 128
#define BN 128
#define BK 32

__device__ __forceinline__ unsigned short f2bf(float f) {
    union { float f; unsigned int u; } x; x.f = f;
    unsigned int u = x.u;
    return (unsigned short)((u + 0x7fffu + ((u >> 16) & 1u)) >> 16);
}

__device__ __forceinline__ void gload16(const void* g, void* l) {
    __builtin_amdgcn_global_load_lds(
        (const __attribute__((address_space(1))) void*)(uintptr_t)g,
        (__attribute__((address_space(3))) void*)(uintptr_t)l,
        16, 0, 0);
}

// pack (c = sigmoid(-gate), v = sigmoid(gate)*g(hidden)) as half2 in a uint
__device__ __forceinline__ unsigned int packCV(float hid, float gat) {
    float e  = __expf(gat);
    float c  = __builtin_amdgcn_rcpf(1.f + e);          // sigmoid(-gate)
    float gg = (hid >= 0.f) ? (hid + 0.5f)
                            : __builtin_amdgcn_rcpf(1.f + __expf(-hid));
    float v  = (1.f - c) * gg;                           // sigmoid(gate)*g(hidden)
    union { f16x2 h; unsigned int u; } pk;
    pk.h[0] = (_Float16)c; pk.h[1] = (_Float16)v;
    return pk.u;
}

// ---------------- conversion + lookback-state init (grid-strided, 8x ILP) -----
// blocks [0,2048): x -> bf16 (8 float4/thread)
// blocks [2048,2304): W interleave -> bf16 (8 float4/thread)
// blocks [2304,2368): segAgg sentinel init (8 u64/thread)
__global__ __launch_bounds__(256)
void cvt_xw(const float* __restrict__ x, unsigned short* __restrict__ xb,
            const float* __restrict__ w, unsigned short* __restrict__ wb,
            unsigned long long* __restrict__ segAgg) {
    const int b = blockIdx.x;
    const int t = threadIdx.x;
    if (b < 2048) {
        // x: 4,194,304 float4 total; 2048 per block; 8 per thread (indep chains)
        const float4* xp = (const float4*)x + (size_t)b * 2048 + t;
        ushort4*      op = (ushort4*)xb + (size_t)b * 2048 + t;
        float4 f[8];
#pragma unroll
        for (int k = 0; k < 8; k++) f[k] = xp[(size_t)k * 256];
#pragma unroll
        for (int k = 0; k < 8; k++) {
            ushort4 o;
            o.x = f2bf(f[k].x); o.y = f2bf(f[k].y);
            o.z = f2bf(f[k].z); o.w = f2bf(f[k].w);
            op[(size_t)k * 256] = o;
        }
    } else if (b < 2304) {
        // W: 524,288 float4 total; 2048 per block; 8 per thread
        const int base4 = (b - 2048) * 2048 + t;    // float4 index into [E_,K_]
        float4 f[8];
        const float* srcs[8];
#pragma unroll
        for (int k = 0; k < 8; k++) {
            int i = (base4 + k * 256) * 4;
            int r = i >> 10;            // row in interleaved [E_, K_]
            int kk = i & 1023;
            int d = r >> 1, g = r & 1;
            srcs[k] = w + (size_t)(g * D_ + d) * K_ + kk;
        }
#pragma unroll
        for (int k = 0; k < 8; k++) f[k] = *(const float4*)srcs[k];
#pragma unroll
        for (int k = 0; k < 8; k++) {
            int i = (base4 + k * 256) * 4;
            ushort4 o;
            o.x = f2bf(f[k].x); o.y = f2bf(f[k].y);
            o.z = f2bf(f[k].z); o.w = f2bf(f[k].w);
            *(ushort4*)(wb + i) = o;
        }
    } else {
        // sentinel: 131072 u64 = 64 blocks * 256 threads * 8
        const size_t base = (size_t)(b - 2304) * 2048 + t;
#pragma unroll
        for (int k = 0; k < 8; k++) segAgg[base + (size_t)k * 256] = SENT;
    }
}

// one K-step: frags from (Ab,Bb) -> 16 MFMAs into acc
__device__ __forceinline__ void kstep(const unsigned short* Ab, const unsigned short* Bb,
                                      int waveM, int waveN, int mrow, int kg,
                                      f32x4 acc[4][4]) {
    bf16x8 af[4], bfr[4];
#pragma unroll
    for (int i = 0; i < 4; i++)
        af[i] = *(const bf16x8*)(Ab + (size_t)(waveM + i * 16 + mrow) * BK + kg);
#pragma unroll
    for (int j = 0; j < 4; j++)
        bfr[j] = *(const bf16x8*)(Bb + (size_t)(waveN + j * 16 + mrow) * BK + kg);
#pragma unroll
    for (int i = 0; i < 4; i++)
#pragma unroll
        for (int j = 0; j < 4; j++)
            acc[i][j] = __builtin_amdgcn_mfma_f32_16x16x32_bf16(af[i], bfr[j], acc[i][j], 0, 0, 0);
}

// ---------------- GEMM + activation + in-block scan/apply (decoupled lookback) --
// LDS union: {A0,A1,B0,B1 dbuf 32KB} overlaid by {Ep 36KB} (Ep live only after
// K-loop); + scratch/hpre 2.25KB => 39.4KB total, 3 blocks/CU (VGPR-capped).
__global__ __launch_bounds__(256, 3)
void gemm_fused(const unsigned short* __restrict__ xb,
                const unsigned short* __restrict__ wb,
                unsigned long long* __restrict__ segAgg,
                float* __restrict__ out) {
    __shared__ __align__(16) char smem[39424];
    unsigned short* A0 = (unsigned short*)(smem);            // 8KB
    unsigned short* A1 = (unsigned short*)(smem + 8192);     // 8KB
    unsigned short* Bc0 = (unsigned short*)(smem + 16384);   // 8KB
    unsigned short* Bc1 = (unsigned short*)(smem + 24576);   // 8KB
    unsigned int*   EpBase = (unsigned int*)(smem);          // [4][64][36] = 36KB overlay
    float* scratch = (float*)(smem + 36864);                 // [4][64][2] = 2KB
    float* hpre    = (float*)(smem + 38912);                 // 64 floats

    // ord = s*64 + (eB*4 + bat): chain position s SLOWEST (lookback-safe,
    // predecessors in earlier scheduling rounds). XCD j (= ord%8) gets bat=j&3
    // and the 8 eB panels of parity j>>2 -> 2MB wb per XCD L2-resident.
    const int ord   = blockIdx.x;       // 0..2047
    const int inner = ord & 63;
    const int eB    = inner >> 2;       // 0..15
    const int bat   = inner & 3;        // 0..3
    const int sIx   = ord >> 6;         // 0..31 chain position within batch
    const int mB    = bat * NCHAIN + sIx;
    const int mBase = mB * BM;
    const int eBase = eB * BN;

    const int tid  = threadIdx.x;
    const int lane = tid & 63;
    const int w    = tid >> 6;
    const int waveM = (w >> 1) * 64;
    const int waveN = (w & 1) * 64;

    f32x4 acc[4][4] = {};

    // staging: thread tid covers (row = tid>>2, 16B chunk = tid&3); LDS dest
    // offset = tid*8 shorts -> wave-uniform base + lane*16B (gload_lds rule).
    const int row0 = tid >> 2, cu = tid & 3;
    const unsigned short* aG0 = xb + (size_t)(mBase + row0) * K_ + cu * 8;
    const unsigned short* aG1 = aG0 + (size_t)64 * K_;
    const unsigned short* bG0 = wb + (size_t)(eBase + row0) * K_ + cu * 8;
    const unsigned short* bG1 = bG0 + (size_t)64 * K_;
    const int woff = w * 512;           // wave-uniform LDS base (shorts)

    const int mrow = lane & 15;
    const int kg   = (lane >> 4) * 8;

    // ---- K-loop: double-buffered, ONE barrier per K-step.
    // Per step: issue next-tile gload_lds into buf^1, ds_read cur buf, MFMA
    // (covers loads in flight), __syncthreads (vmcnt0+lgkm0: next tile landed,
    // all waves done reading cur). Round-6 had 2 barriers/step; this removes
    // the mid-step rendezvous.
#define STAGE(Ab, Bb, kk) do { \
        gload16(aG0 + (kk), (Ab) + woff); \
        gload16(aG1 + (kk), (Ab) + 2048 + woff); \
        gload16(bG0 + (kk), (Bb) + woff); \
        gload16(bG1 + (kk), (Bb) + 2048 + woff); \
    } while (0)

    STAGE(A0, Bc0, 0);
    __syncthreads();                       // tile 0 staged

    for (int k0 = 0; k0 < K_; k0 += 2 * BK) {
        // phase A: stage tile k0+BK into buf1, compute tile k0 from buf0
        STAGE(A1, Bc1, k0 + BK);
        __builtin_amdgcn_sched_barrier(0); // pin stage-issue above reads/MFMA
        kstep(A0, Bc0, waveM, waveN, mrow, kg, acc);
        __syncthreads();
        // phase B: stage tile k0+2BK into buf0, compute tile k0+BK from buf1
        if (k0 + 2 * BK < K_) {
            STAGE(A0, Bc0, k0 + 2 * BK);
            __builtin_amdgcn_sched_barrier(0);
        }
        kstep(A1, Bc1, waveM, waveN, mrow, kg, acc);
        __syncthreads();
    }
#undef STAGE

    // ---- epilogue 1: activation + pack + LDS transpose (Ep overlays dbuf;
    // all LDS reads drained by the final K-loop barrier) ----
    const int q    = lane >> 4;
    const int odd  = lane & 1;
    const int colL = (lane & 15) >> 1;            // 0..7
    unsigned int* EpW = EpBase + w * (64 * 36);

#pragma unroll
    for (int i = 0; i < 4; i++) {
#pragma unroll
        for (int j = 0; j < 4; j++) {
            float o0 = __shfl_xor(acc[i][j][0], 1, 64);
            float o1 = __shfl_xor(acc[i][j][1], 1, 64);
            float o2 = __shfl_xor(acc[i][j][2], 1, 64);
            float o3 = __shfl_xor(acc[i][j][3], 1, 64);
            float m0 = odd ? acc[i][j][2] : acc[i][j][0];
            float m1 = odd ? acc[i][j][3] : acc[i][j][1];
            float p0 = odd ? o2 : o0;
            float p1 = odd ? o3 : o1;
            float h0 = odd ? p0 : m0, g0 = odd ? m0 : p0;
            float h1 = odd ? p1 : m1, g1 = odd ? m1 : p1;
            int row = i * 16 + q * 4 + odd * 2;
            int col = j * 8 + colL;
            EpW[(row    ) * 36 + col] = packCV(h0, g0);
            EpW[(row + 1) * 36 + col] = packCV(h1, g1);
        }
    }

    // ---- epilogue 2: quarter reduce (32 rows x 64 ch per thread-group) ----
    __syncthreads();                      // Ep fully written

    const int dl = tid & 63;              // channel 0..63 within block
    const int qt = tid >> 6;              // quarter 0..3 (rows qt*32 .. +31)
    const int wq = (qt >> 1) * 2 + (dl >> 5);
    const int rB = (qt & 1) * 32;
    const int cc_ = dl & 31;
    const unsigned int* src = EpBase + ((size_t)wq * 64 + rB) * 36 + cc_;
    {
        float C = 1.f, V = 0.f;
#pragma unroll 8
        for (int rr = 0; rr < 32; rr++) {
            union { unsigned int u; f16x2 h; } uu;
            uu.u = src[rr * 36];
            float cv_c = (float)uu.h[0], cv_v = (float)uu.h[1];
            V = fmaf(cv_c, V, cv_v);
            C *= cv_c;
        }
        scratch[(qt * 64 + dl) * 2 + 0] = C;
        scratch[(qt * 64 + dl) * 2 + 1] = V;
    }
    __syncthreads();

    // ---- epilogue 3 (wave 0 only): publish aggregate, then lookback ----
    // Relaxed agent-scope 8B atomic publish: the payload IS the data
    // (sentinel-validated); no fence (round-2's fence caused L2 inv: -35us).
    if (tid < 64) {
        float C0 = scratch[(0 * 64 + tid) * 2], V0 = scratch[(0 * 64 + tid) * 2 + 1];
        float C1 = scratch[(1 * 64 + tid) * 2], V1 = scratch[(1 * 64 + tid) * 2 + 1];
        float C2 = scratch[(2 * 64 + tid) * 2], V2 = scratch[(2 * 64 + tid) * 2 + 1];
        float C3 = scratch[(3 * 64 + tid) * 2], V3 = scratch[(3 * 64 + tid) * 2 + 1];
        float Cb = (C0 * C1) * (C2 * C3);
        float Vb = fmaf(C3, fmaf(C2, fmaf(C1, V0, V1), V2), V3);
        union { unsigned long long u; float f[2]; } pk;
        pk.f[0] = Cb; pk.f[1] = Vb;
        // UNCONDITIONAL publish before any wait -> no deadlock possible.
        __hip_atomic_store(&segAgg[(size_t)ord * 64 + tid], pk.u,
                           __ATOMIC_RELAXED, __HIP_MEMORY_SCOPE_AGENT);

        // aggregate-only lookback: fold predecessors t = 0..sIx-1 in order.
        float h = 0.f;
        const size_t chanB = (size_t)inner * 64 + tid;  // (eB*4+bat)*64+ch
#pragma unroll 1
        for (int t0 = 0; t0 < NCHAIN; t0 += 8) {
            if (t0 >= sIx) break;
            unsigned long long vb[8];
#pragma unroll
            for (int k = 0; k < 8; k++)
                vb[k] = (t0 + k < sIx)
                    ? __hip_atomic_load(&segAgg[(size_t)(t0 + k) * 4096 + chanB],
                                        __ATOMIC_RELAXED, __HIP_MEMORY_SCOPE_AGENT)
                    : 0x3f800000ull;    // identity (C=1, V=0)
#pragma unroll
            for (int k = 0; k < 8; k++) {
                if (t0 + k < sIx) {
                    while (vb[k] == SENT)
                        vb[k] = __hip_atomic_load(&segAgg[(size_t)(t0 + k) * 4096 + chanB],
                                                  __ATOMIC_RELAXED, __HIP_MEMORY_SCOPE_AGENT);
                }
            }
#pragma unroll
            for (int k = 0; k < 8; k++) {
                union { unsigned long long u; float f[2]; } qd; qd.u = vb[k];
                h = fmaf(qd.f[0], h, qd.f[1]);
            }
        }
        hpre[tid] = h;
    }
    __syncthreads();

    // ---- epilogue 4: apply h_t = c_t*h_{t-1} + v_t, write out (fp32, NT
    // stores: 64MB stream must not evict wb panels from per-XCD L2) ----
    {
        float h = hpre[dl];
        if (qt > 0) h = fmaf(scratch[(0 * 64 + dl) * 2], h, scratch[(0 * 64 + dl) * 2 + 1]);
        if (qt > 1) h = fmaf(scratch[(1 * 64 + dl) * 2], h, scratch[(1 * 64 + dl) * 2 + 1]);
        if (qt > 2) h = fmaf(scratch[(2 * 64 + dl) * 2], h, scratch[(2 * 64 + dl) * 2 + 1]);
        float* outp = out + (size_t)(mBase + qt * 32) * D_ + (eB * 64 + dl);
#pragma unroll 8
        for (int rr = 0; rr < 32; rr++) {
            union { unsigned int u; f16x2 hh; } uu;
            uu.u = src[rr * 36];
            h = fmaf((float)uu.hh[0], h, (float)uu.hh[1]);
            __builtin_nontemporal_store(h, outp + (size_t)rr * D_);
        }
    }
}

// ---------------- launch ----------------
extern "C" void kernel_launch(void* const* d_in, const int* in_sizes, int n_in,
                              void* d_out, int out_size, void* d_ws, size_t ws_size,
                              hipStream_t stream) {
    const float* x = (const float*)d_in[0];
    const float* wmat = (const float*)d_in[1];
    float* out = (float*)d_out;
    char* ws = (char*)d_ws;

    unsigned short* xb = (unsigned short*)(ws);                       // 32 MB @ 0
    unsigned short* wb = (unsigned short*)(ws + (32u << 20));         //  4 MB @ 32M
    unsigned long long* segAgg = (unsigned long long*)(ws + (36u << 20)); // 1 MB @ 36M

    cvt_xw<<<2368, 256, 0, stream>>>(x, xb, wmat, wb, segAgg);
    gemm_fused<<<2048, 256, 0, stream>>>(xb, wb, segAgg, out);
}

// Round 8
// 198.498 us; speedup vs baseline: 1.2079x; 1.0230x over previous
//
#include <hip/hip_runtime.h>
#include <stdint.h>

#define B_ 4
#define S_ 4096
#define D_ 1024
#define E_ 2048          // 2*D
#define K_ 1024
#define M_ (B_*S_)       // 16384
#define NCHAIN 32        // 128-row tiles per batch = chain length
#define SENT 0xFFFFFFFFFFFFFFFFull

typedef __bf16 bf16x8 __attribute__((ext_vector_type(8)));
typedef float  f32x4  __attribute__((ext_vector_type(4)));
typedef _Float16 f16x2 __attribute__((ext_vector_type(2)));

#define BM 128
#define BN 128
#define BK 32

__device__ __forceinline__ unsigned short f2bf(float f) {
    union { float f; unsigned int u; } x; x.f = f;
    unsigned int u = x.u;
    return (unsigned short)((u + 0x7fffu + ((u >> 16) & 1u)) >> 16);
}

__device__ __forceinline__ void gload16(const void* g, void* l) {
    __builtin_amdgcn_global_load_lds(
        (const __attribute__((address_space(1))) void*)(uintptr_t)g,
        (__attribute__((address_space(3))) void*)(uintptr_t)l,
        16, 0, 0);
}

// pack (c = sigmoid(-gate), v = sigmoid(gate)*g(hidden)) as half2 in a uint
__device__ __forceinline__ unsigned int packCV(float hid, float gat) {
    float e  = __expf(gat);
    float c  = __builtin_amdgcn_rcpf(1.f + e);          // sigmoid(-gate)
    float gg = (hid >= 0.f) ? (hid + 0.5f)
                            : __builtin_amdgcn_rcpf(1.f + __expf(-hid));
    float v  = (1.f - c) * gg;                           // sigmoid(gate)*g(hidden)
    union { f16x2 h; unsigned int u; } pk;
    pk.h[0] = (_Float16)c; pk.h[1] = (_Float16)v;
    return pk.u;
}

// ---------------- conversion + lookback-state init (grid-strided, 8x ILP) -----
__global__ __launch_bounds__(256)
void cvt_xw(const float* __restrict__ x, unsigned short* __restrict__ xb,
            const float* __restrict__ w, unsigned short* __restrict__ wb,
            unsigned long long* __restrict__ segAgg) {
    const int b = blockIdx.x;
    const int t = threadIdx.x;
    if (b < 2048) {
        const float4* xp = (const float4*)x + (size_t)b * 2048 + t;
        ushort4*      op = (ushort4*)xb + (size_t)b * 2048 + t;
        float4 f[8];
#pragma unroll
        for (int k = 0; k < 8; k++) f[k] = xp[(size_t)k * 256];
#pragma unroll
        for (int k = 0; k < 8; k++) {
            ushort4 o;
            o.x = f2bf(f[k].x); o.y = f2bf(f[k].y);
            o.z = f2bf(f[k].z); o.w = f2bf(f[k].w);
            op[(size_t)k * 256] = o;
        }
    } else if (b < 2304) {
        const int base4 = (b - 2048) * 2048 + t;    // float4 index into [E_,K_]
        float4 f[8];
        const float* srcs[8];
#pragma unroll
        for (int k = 0; k < 8; k++) {
            int i = (base4 + k * 256) * 4;
            int r = i >> 10;
            int kk = i & 1023;
            int d = r >> 1, g = r & 1;
            srcs[k] = w + (size_t)(g * D_ + d) * K_ + kk;
        }
#pragma unroll
        for (int k = 0; k < 8; k++) f[k] = *(const float4*)srcs[k];
#pragma unroll
        for (int k = 0; k < 8; k++) {
            int i = (base4 + k * 256) * 4;
            ushort4 o;
            o.x = f2bf(f[k].x); o.y = f2bf(f[k].y);
            o.z = f2bf(f[k].z); o.w = f2bf(f[k].w);
            *(ushort4*)(wb + i) = o;
        }
    } else {
        const size_t base = (size_t)(b - 2304) * 2048 + t;
#pragma unroll
        for (int k = 0; k < 8; k++) segAgg[base + (size_t)k * 256] = SENT;
    }
}

// one K-step: frags from (Ab,Bb) -> 16 MFMAs into acc. kgx = swizzled chunk
// offset (shorts): chunk = (lane>>4) ^ ((mrow>>1)&3) — see staging swizzle.
__device__ __forceinline__ void kstep(const unsigned short* Ab, const unsigned short* Bb,
                                      int waveM, int waveN, int mrow, int kgx,
                                      f32x4 acc[4][4]) {
    bf16x8 af[4], bfr[4];
#pragma unroll
    for (int i = 0; i < 4; i++)
        af[i] = *(const bf16x8*)(Ab + (size_t)(waveM + i * 16 + mrow) * BK + kgx);
#pragma unroll
    for (int j = 0; j < 4; j++)
        bfr[j] = *(const bf16x8*)(Bb + (size_t)(waveN + j * 16 + mrow) * BK + kgx);
#pragma unroll
    for (int i = 0; i < 4; i++)
#pragma unroll
        for (int j = 0; j < 4; j++)
            acc[i][j] = __builtin_amdgcn_mfma_f32_16x16x32_bf16(af[i], bfr[j], acc[i][j], 0, 0, 0);
}

// ---------------- GEMM + activation + in-block scan/apply (decoupled lookback) --
// 3-buffer 2-deep pipeline, counted vmcnt (T4); LDS bufs 48KB overlaid by Ep
// 36KB (live only post-loop); + scratch 2.25KB => 50.25KB, 3 blocks/CU.
// Frag-read bank swizzle (T2, rule #21 both-sides): LDS(row, c) holds global
// chunk c ^ ((row>>1)&3); applied on the GLOBAL source addr at staging (LDS
// dest must stay linear for global_load_lds) and on the frag-read chunk.
__global__ __launch_bounds__(256, 3)
void gemm_fused(const unsigned short* __restrict__ xb,
                const unsigned short* __restrict__ wb,
                unsigned long long* __restrict__ segAgg,
                float* __restrict__ out) {
    __shared__ __align__(16) char smem[51456];
    unsigned short* A0 = (unsigned short*)(smem);            // 8KB each
    unsigned short* A1 = (unsigned short*)(smem + 8192);
    unsigned short* A2 = (unsigned short*)(smem + 16384);
    unsigned short* B0 = (unsigned short*)(smem + 24576);
    unsigned short* B1 = (unsigned short*)(smem + 32768);
    unsigned short* B2 = (unsigned short*)(smem + 40960);
    unsigned int*   EpBase = (unsigned int*)(smem);          // [4][64][36]=36KB overlay
    float* scratch = (float*)(smem + 49152);                 // [4][64][2] = 2KB
    float* hpre    = (float*)(smem + 51200);                 // 64 floats

    // ord = s*64 + (eB*4 + bat): chain position s SLOWEST (lookback-safe).
    // XCD j (= ord%8) gets bat=j&3 + 8 eB panels of parity j>>2.
    const int ord   = blockIdx.x;       // 0..2047
    const int inner = ord & 63;
    const int eB    = inner >> 2;       // 0..15
    const int bat   = inner & 3;        // 0..3
    const int sIx   = ord >> 6;         // 0..31 chain position within batch
    const int mB    = bat * NCHAIN + sIx;
    const int mBase = mB * BM;
    const int eBase = eB * BN;

    const int tid  = threadIdx.x;
    const int lane = tid & 63;
    const int w    = tid >> 6;
    const int waveM = (w >> 1) * 64;
    const int waveN = (w & 1) * 64;

    f32x4 acc[4][4] = {};

    // staging: thread tid covers (row = tid>>2, LDS chunk c_l = tid&3); its
    // GLOBAL chunk is swizzled: c_g = c_l ^ ((row>>1)&3). (row+64 keeps the
    // same XOR since 32&3==0, so one base serves both halves.)
    const int row0 = tid >> 2, cu = tid & 3;
    const int cg   = cu ^ ((row0 >> 1) & 3);
    const unsigned short* aG0 = xb + (size_t)(mBase + row0) * K_ + cg * 8;
    const unsigned short* aG1 = aG0 + (size_t)64 * K_;
    const unsigned short* bG0 = wb + (size_t)(eBase + row0) * K_ + cg * 8;
    const unsigned short* bG1 = bG0 + (size_t)64 * K_;
    const int woff = w * 512;           // wave-uniform LDS base (shorts)

    const int mrow = lane & 15;
    // frag-read chunk, same XOR; independent of i/waveM (both shift row by
    // multiples of 16 -> (row>>1)&3 unchanged) -> one constant per lane.
    const int kgx  = (((lane >> 4) ^ ((mrow >> 1) & 3))) * 8;

#define STAGE(Ab, Bb, kk) do { \
        gload16(aG0 + (kk), (Ab) + woff); \
        gload16(aG1 + (kk), (Ab) + 2048 + woff); \
        gload16(bG0 + (kk), (Bb) + woff); \
        gload16(bG1 + (kk), (Bb) + 2048 + woff); \
    } while (0)

    // ---- K-loop: 32 tiles, 2-deep prefetch, one barrier per tile.
    // Steady state: after STAGE(t+2), outstanding = 8 (tiles t+1,t+2);
    // vmcnt(4) waits the 4 OLDEST (tile t+1) -> landed; newest 4 stay in
    // flight across the barrier (never drain to 0 mid-loop). lgkmcnt(0)
    // guarantees this wave's frag reads done before others overwrite.
#define STEP_MID(CA, CB, SA, SB, kks) do { \
        STAGE(SA, SB, (kks)); \
        __builtin_amdgcn_sched_barrier(0); \
        kstep(CA, CB, waveM, waveN, mrow, kgx, acc); \
        asm volatile("s_waitcnt vmcnt(4) lgkmcnt(0)" ::: "memory"); \
        __builtin_amdgcn_s_barrier(); \
    } while (0)

    STAGE(A0, B0, 0);
    STAGE(A1, B1, BK);
    asm volatile("s_waitcnt vmcnt(4)" ::: "memory");   // tile 0 (oldest 4) landed
    __builtin_amdgcn_s_barrier();

    for (int t = 0; t < 30; t += 3) {
        const int kk = t * BK;
        STEP_MID(A0, B0, A2, B2, kk + 2 * BK);   // compute t,   stage t+2
        STEP_MID(A1, B1, A0, B0, kk + 3 * BK);   // compute t+1, stage t+3
        STEP_MID(A2, B2, A1, B1, kk + 4 * BK);   // compute t+2, stage t+4
    }
    // tiles 30 (buf0) and 31 (buf1); drain to 0 at the tail.
    kstep(A0, B0, waveM, waveN, mrow, kgx, acc);
    asm volatile("s_waitcnt vmcnt(0) lgkmcnt(0)" ::: "memory");
    __builtin_amdgcn_s_barrier();
    kstep(A1, B1, waveM, waveN, mrow, kgx, acc);
    asm volatile("s_waitcnt lgkmcnt(0)" ::: "memory"); // all frag reads done
    __builtin_amdgcn_s_barrier();                      // before Ep overlay
#undef STEP_MID
#undef STAGE

    // ---- epilogue 1: activation + pack + LDS transpose (Ep overlays bufs) ----
    const int q    = lane >> 4;
    const int odd  = lane & 1;
    const int colL = (lane & 15) >> 1;            // 0..7
    unsigned int* EpW = EpBase + w * (64 * 36);

#pragma unroll
    for (int i = 0; i < 4; i++) {
#pragma unroll
        for (int j = 0; j < 4; j++) {
            float o0 = __shfl_xor(acc[i][j][0], 1, 64);
            float o1 = __shfl_xor(acc[i][j][1], 1, 64);
            float o2 = __shfl_xor(acc[i][j][2], 1, 64);
            float o3 = __shfl_xor(acc[i][j][3], 1, 64);
            float m0 = odd ? acc[i][j][2] : acc[i][j][0];
            float m1 = odd ? acc[i][j][3] : acc[i][j][1];
            float p0 = odd ? o2 : o0;
            float p1 = odd ? o3 : o1;
            float h0 = odd ? p0 : m0, g0 = odd ? m0 : p0;
            float h1 = odd ? p1 : m1, g1 = odd ? m1 : p1;
            int row = i * 16 + q * 4 + odd * 2;
            int col = j * 8 + colL;
            EpW[(row    ) * 36 + col] = packCV(h0, g0);
            EpW[(row + 1) * 36 + col] = packCV(h1, g1);
        }
    }

    // ---- epilogue 2: quarter reduce (32 rows x 64 ch per thread-group) ----
    __syncthreads();                      // Ep fully written

    const int dl = tid & 63;              // channel 0..63 within block
    const int qt = tid >> 6;              // quarter 0..3 (rows qt*32 .. +31)
    const int wq = (qt >> 1) * 2 + (dl >> 5);
    const int rB = (qt & 1) * 32;
    const int cc_ = dl & 31;
    const unsigned int* src = EpBase + ((size_t)wq * 64 + rB) * 36 + cc_;
    {
        float C = 1.f, V = 0.f;
#pragma unroll 8
        for (int rr = 0; rr < 32; rr++) {
            union { unsigned int u; f16x2 h; } uu;
            uu.u = src[rr * 36];
            float cv_c = (float)uu.h[0], cv_v = (float)uu.h[1];
            V = fmaf(cv_c, V, cv_v);
            C *= cv_c;
        }
        scratch[(qt * 64 + dl) * 2 + 0] = C;
        scratch[(qt * 64 + dl) * 2 + 1] = V;
    }
    __syncthreads();

    // ---- epilogue 3 (wave 0 only): publish aggregate, then lookback ----
    // Relaxed agent-scope 8B atomic publish: the payload IS the data
    // (sentinel-validated); no fence (round-2's fence caused L2 inv: -35us).
    if (tid < 64) {
        float C0 = scratch[(0 * 64 + tid) * 2], V0 = scratch[(0 * 64 + tid) * 2 + 1];
        float C1 = scratch[(1 * 64 + tid) * 2], V1 = scratch[(1 * 64 + tid) * 2 + 1];
        float C2 = scratch[(2 * 64 + tid) * 2], V2 = scratch[(2 * 64 + tid) * 2 + 1];
        float C3 = scratch[(3 * 64 + tid) * 2], V3 = scratch[(3 * 64 + tid) * 2 + 1];
        float Cb = (C0 * C1) * (C2 * C3);
        float Vb = fmaf(C3, fmaf(C2, fmaf(C1, V0, V1), V2), V3);
        union { unsigned long long u; float f[2]; } pk;
        pk.f[0] = Cb; pk.f[1] = Vb;
        // UNCONDITIONAL publish before any wait -> no deadlock possible.
        __hip_atomic_store(&segAgg[(size_t)ord * 64 + tid], pk.u,
                           __ATOMIC_RELAXED, __HIP_MEMORY_SCOPE_AGENT);

        // aggregate-only lookback: fold predecessors t = 0..sIx-1 in order.
        float h = 0.f;
        const size_t chanB = (size_t)inner * 64 + tid;  // (eB*4+bat)*64+ch
#pragma unroll 1
        for (int t0 = 0; t0 < NCHAIN; t0 += 8) {
            if (t0 >= sIx) break;
            unsigned long long vb[8];
#pragma unroll
            for (int k = 0; k < 8; k++)
                vb[k] = (t0 + k < sIx)
                    ? __hip_atomic_load(&segAgg[(size_t)(t0 + k) * 4096 + chanB],
                                        __ATOMIC_RELAXED, __HIP_MEMORY_SCOPE_AGENT)
                    : 0x3f800000ull;    // identity (C=1, V=0)
#pragma unroll
            for (int k = 0; k < 8; k++) {
                if (t0 + k < sIx) {
                    while (vb[k] == SENT)
                        vb[k] = __hip_atomic_load(&segAgg[(size_t)(t0 + k) * 4096 + chanB],
                                                  __ATOMIC_RELAXED, __HIP_MEMORY_SCOPE_AGENT);
                }
            }
#pragma unroll
            for (int k = 0; k < 8; k++) {
                union { unsigned long long u; float f[2]; } qd; qd.u = vb[k];
                h = fmaf(qd.f[0], h, qd.f[1]);
            }
        }
        hpre[tid] = h;
    }
    __syncthreads();

    // ---- epilogue 4: apply h_t = c_t*h_{t-1} + v_t, write out (fp32, NT
    // stores: 64MB stream must not evict wb panels from per-XCD L2) ----
    {
        float h = hpre[dl];
        if (qt > 0) h = fmaf(scratch[(0 * 64 + dl) * 2], h, scratch[(0 * 64 + dl) * 2 + 1]);
        if (qt > 1) h = fmaf(scratch[(1 * 64 + dl) * 2], h, scratch[(1 * 64 + dl) * 2 + 1]);
        if (qt > 2) h = fmaf(scratch[(2 * 64 + dl) * 2], h, scratch[(2 * 64 + dl) * 2 + 1]);
        float* outp = out + (size_t)(mBase + qt * 32) * D_ + (eB * 64 + dl);
#pragma unroll 8
        for (int rr = 0; rr < 32; rr++) {
            union { unsigned int u; f16x2 hh; } uu;
            uu.u = src[rr * 36];
            h = fmaf((float)uu.hh[0], h, (float)uu.hh[1]);
            __builtin_nontemporal_store(h, outp + (size_t)rr * D_);
        }
    }
}

// ---------------- launch ----------------
extern "C" void kernel_launch(void* const* d_in, const int* in_sizes, int n_in,
                              void* d_out, int out_size, void* d_ws, size_t ws_size,
                              hipStream_t stream) {
    const float* x = (const float*)d_in[0];
    const float* wmat = (const float*)d_in[1];
    float* out = (float*)d_out;
    char* ws = (char*)d_ws;

    unsigned short* xb = (unsigned short*)(ws);                       // 32 MB @ 0
    unsigned short* wb = (unsigned short*)(ws + (32u << 20));         //  4 MB @ 32M
    unsigned long long* segAgg = (unsigned long long*)(ws + (36u << 20)); // 1 MB @ 36M

    cvt_xw<<<2368, 256, 0, stream>>>(x, xb, wmat, wb, segAgg);
    gemm_fused<<<2048, 256, 0, stream>>>(xb, wb, segAgg, out);
}

// Round 9
// 198.438 us; speedup vs baseline: 1.2083x; 1.0003x over previous
//
#include <hip/hip_runtime.h>
#include <stdint.h>

#define B_ 4
#define S_ 4096
#define D_ 1024
#define E_ 2048          // 2*D
#define K_ 1024
#define M_ (B_*S_)       // 16384
#define NCHAIN 32        // 128-row tiles per batch = chain length
#define SENT 0xFFFFFFFFFFFFFFFFull

typedef __bf16 bf16x8 __attribute__((ext_vector_type(8)));
typedef float  f32x4  __attribute__((ext_vector_type(4)));
typedef _Float16 f16x2 __attribute__((ext_vector_type(2)));

#define BM 128
#define BN 128
#define BK 32

__device__ __forceinline__ unsigned short f2bf(float f) {
    union { float f; unsigned int u; } x; x.f = f;
    unsigned int u = x.u;
    return (unsigned short)((u + 0x7fffu + ((u >> 16) & 1u)) >> 16);
}

__device__ __forceinline__ void gload16(const void* g, void* l) {
    __builtin_amdgcn_global_load_lds(
        (const __attribute__((address_space(1))) void*)(uintptr_t)g,
        (__attribute__((address_space(3))) void*)(uintptr_t)l,
        16, 0, 0);
}

// pack (c = sigmoid(-gate), v = sigmoid(gate)*g(hidden)) as half2 in a uint
__device__ __forceinline__ unsigned int packCV(float hid, float gat) {
    float e  = __expf(gat);
    float c  = __builtin_amdgcn_rcpf(1.f + e);          // sigmoid(-gate)
    float gg = (hid >= 0.f) ? (hid + 0.5f)
                            : __builtin_amdgcn_rcpf(1.f + __expf(-hid));
    float v  = (1.f - c) * gg;                           // sigmoid(gate)*g(hidden)
    union { f16x2 h; unsigned int u; } pk;
    pk.h[0] = (_Float16)c; pk.h[1] = (_Float16)v;
    return pk.u;
}

// ---------------- conversion + lookback-state init (grid-strided, 8x ILP) -----
__global__ __launch_bounds__(256)
void cvt_xw(const float* __restrict__ x, unsigned short* __restrict__ xb,
            const float* __restrict__ w, unsigned short* __restrict__ wb,
            unsigned long long* __restrict__ segAgg) {
    const int b = blockIdx.x;
    const int t = threadIdx.x;
    if (b < 2048) {
        const float4* xp = (const float4*)x + (size_t)b * 2048 + t;
        ushort4*      op = (ushort4*)xb + (size_t)b * 2048 + t;
        float4 f[8];
#pragma unroll
        for (int k = 0; k < 8; k++) f[k] = xp[(size_t)k * 256];
#pragma unroll
        for (int k = 0; k < 8; k++) {
            ushort4 o;
            o.x = f2bf(f[k].x); o.y = f2bf(f[k].y);
            o.z = f2bf(f[k].z); o.w = f2bf(f[k].w);
            op[(size_t)k * 256] = o;
        }
    } else if (b < 2304) {
        const int base4 = (b - 2048) * 2048 + t;    // float4 index into [E_,K_]
        float4 f[8];
        const float* srcs[8];
#pragma unroll
        for (int k = 0; k < 8; k++) {
            int i = (base4 + k * 256) * 4;
            int r = i >> 10;
            int kk = i & 1023;
            int d = r >> 1, g = r & 1;
            srcs[k] = w + (size_t)(g * D_ + d) * K_ + kk;
        }
#pragma unroll
        for (int k = 0; k < 8; k++) f[k] = *(const float4*)srcs[k];
#pragma unroll
        for (int k = 0; k < 8; k++) {
            int i = (base4 + k * 256) * 4;
            ushort4 o;
            o.x = f2bf(f[k].x); o.y = f2bf(f[k].y);
            o.z = f2bf(f[k].z); o.w = f2bf(f[k].w);
            *(ushort4*)(wb + i) = o;
        }
    } else {
        const size_t base = (size_t)(b - 2304) * 2048 + t;
#pragma unroll
        for (int k = 0; k < 8; k++) segAgg[base + (size_t)k * 256] = SENT;
    }
}

// one K-step: frags from (Ab,Bb) -> 16 MFMAs into acc. kgx = swizzled chunk
// offset (shorts): chunk = (lane>>4) ^ ((mrow>>1)&3) — see staging swizzle.
// T5: setprio(1) around the MFMA cluster — with counted-vmcnt, waves on the
// CU are role-split (stage/read/MFMA), so priority arbitration has teeth.
__device__ __forceinline__ void kstep(const unsigned short* Ab, const unsigned short* Bb,
                                      int waveM, int waveN, int mrow, int kgx,
                                      f32x4 acc[4][4]) {
    bf16x8 af[4], bfr[4];
#pragma unroll
    for (int i = 0; i < 4; i++)
        af[i] = *(const bf16x8*)(Ab + (size_t)(waveM + i * 16 + mrow) * BK + kgx);
#pragma unroll
    for (int j = 0; j < 4; j++)
        bfr[j] = *(const bf16x8*)(Bb + (size_t)(waveN + j * 16 + mrow) * BK + kgx);
    __builtin_amdgcn_s_setprio(1);
#pragma unroll
    for (int i = 0; i < 4; i++)
#pragma unroll
        for (int j = 0; j < 4; j++)
            acc[i][j] = __builtin_amdgcn_mfma_f32_16x16x32_bf16(af[i], bfr[j], acc[i][j], 0, 0, 0);
    __builtin_amdgcn_s_setprio(0);
}

// ---------------- GEMM + activation + in-block scan/apply (decoupled lookback) --
// 3-buffer 2-deep pipeline, counted vmcnt (T4); LDS 48KB total: bufs 48KB
// overlaid post-loop by Ep 36KB + scratch/hpre 2.25KB. 3 blocks/CU.
// Frag-read bank swizzle (T2, rule #21 both-sides): LDS(row, c) holds global
// chunk c ^ ((row>>1)&3); applied on the GLOBAL source addr at staging (LDS
// dest must stay linear for global_load_lds) and on the frag-read chunk.
// (Verified round 8: SQ_LDS_BANK_CONFLICT 8.4M -> 0.)
__global__ __launch_bounds__(256, 3)
void gemm_fused(const unsigned short* __restrict__ xb,
                const unsigned short* __restrict__ wb,
                unsigned long long* __restrict__ segAgg,
                float* __restrict__ out) {
    __shared__ __align__(16) char smem[49152];
    unsigned short* A0 = (unsigned short*)(smem);            // 8KB each
    unsigned short* A1 = (unsigned short*)(smem + 8192);
    unsigned short* A2 = (unsigned short*)(smem + 16384);
    unsigned short* B0 = (unsigned short*)(smem + 24576);
    unsigned short* B1 = (unsigned short*)(smem + 32768);
    unsigned short* B2 = (unsigned short*)(smem + 40960);
    unsigned int*   EpBase = (unsigned int*)(smem);          // [4][64][36]=36KB overlay
    float* scratch = (float*)(smem + 36864);                 // 2KB (overlays B1/B2, dead post-loop)
    float* hpre    = (float*)(smem + 38912);                 // 64 floats

    // ord = s*64 + (eB*4 + bat): chain position s SLOWEST (lookback-safe).
    // XCD j (= ord%8) gets bat=j&3 + 8 eB panels of parity j>>2.
    const int ord   = blockIdx.x;       // 0..2047
    const int inner = ord & 63;
    const int eB    = inner >> 2;       // 0..15
    const int bat   = inner & 3;        // 0..3
    const int sIx   = ord >> 6;         // 0..31 chain position within batch
    const int mB    = bat * NCHAIN + sIx;
    const int mBase = mB * BM;
    const int eBase = eB * BN;

    const int tid  = threadIdx.x;
    const int lane = tid & 63;
    const int w    = tid >> 6;
    const int waveM = (w >> 1) * 64;
    const int waveN = (w & 1) * 64;

    f32x4 acc[4][4] = {};

    // staging: thread tid covers (row = tid>>2, LDS chunk c_l = tid&3); its
    // GLOBAL chunk is swizzled: c_g = c_l ^ ((row>>1)&3). (row+64 keeps the
    // same XOR since 32&3==0, so one base serves both halves.)
    const int row0 = tid >> 2, cu = tid & 3;
    const int cg   = cu ^ ((row0 >> 1) & 3);
    const unsigned short* aG0 = xb + (size_t)(mBase + row0) * K_ + cg * 8;
    const unsigned short* aG1 = aG0 + (size_t)64 * K_;
    const unsigned short* bG0 = wb + (size_t)(eBase + row0) * K_ + cg * 8;
    const unsigned short* bG1 = bG0 + (size_t)64 * K_;
    const int woff = w * 512;           // wave-uniform LDS base (shorts)

    const int mrow = lane & 15;
    // frag-read chunk, same XOR; independent of i/waveM (both shift row by
    // multiples of 16 -> (row>>1)&3 unchanged) -> one constant per lane.
    const int kgx  = (((lane >> 4) ^ ((mrow >> 1) & 3))) * 8;

#define STAGE(Ab, Bb, kk) do { \
        gload16(aG0 + (kk), (Ab) + woff); \
        gload16(aG1 + (kk), (Ab) + 2048 + woff); \
        gload16(bG0 + (kk), (Bb) + woff); \
        gload16(bG1 + (kk), (Bb) + 2048 + woff); \
    } while (0)

    // ---- K-loop: 32 tiles, 2-deep prefetch, one barrier per tile.
    // Steady state: after STAGE(t+2), outstanding = 8 (tiles t+1,t+2);
    // vmcnt(4) waits the 4 OLDEST (tile t+1) -> landed; newest 4 stay in
    // flight across the barrier (never drain to 0 mid-loop). lgkmcnt(0)
    // guarantees this wave's frag reads done before others overwrite.
#define STEP_MID(CA, CB, SA, SB, kks) do { \
        STAGE(SA, SB, (kks)); \
        __builtin_amdgcn_sched_barrier(0); \
        kstep(CA, CB, waveM, waveN, mrow, kgx, acc); \
        asm volatile("s_waitcnt vmcnt(4) lgkmcnt(0)" ::: "memory"); \
        __builtin_amdgcn_s_barrier(); \
    } while (0)

    STAGE(A0, B0, 0);
    STAGE(A1, B1, BK);
    asm volatile("s_waitcnt vmcnt(4)" ::: "memory");   // tile 0 (oldest 4) landed
    __builtin_amdgcn_s_barrier();

    for (int t = 0; t < 30; t += 3) {
        const int kk = t * BK;
        STEP_MID(A0, B0, A2, B2, kk + 2 * BK);   // compute t,   stage t+2
        STEP_MID(A1, B1, A0, B0, kk + 3 * BK);   // compute t+1, stage t+3
        STEP_MID(A2, B2, A1, B1, kk + 4 * BK);   // compute t+2, stage t+4
    }
    // tiles 30 (buf0) and 31 (buf1); drain to 0 at the tail.
    kstep(A0, B0, waveM, waveN, mrow, kgx, acc);
    asm volatile("s_waitcnt vmcnt(0) lgkmcnt(0)" ::: "memory");
    __builtin_amdgcn_s_barrier();
    kstep(A1, B1, waveM, waveN, mrow, kgx, acc);
    asm volatile("s_waitcnt lgkmcnt(0)" ::: "memory"); // all frag reads done
    __builtin_amdgcn_s_barrier();                      // before Ep overlay
#undef STEP_MID
#undef STAGE

    // ---- epilogue 1: activation + pack + LDS transpose (Ep overlays bufs) ----
    const int q    = lane >> 4;
    const int odd  = lane & 1;
    const int colL = (lane & 15) >> 1;            // 0..7
    unsigned int* EpW = EpBase + w * (64 * 36);

#pragma unroll
    for (int i = 0; i < 4; i++) {
#pragma unroll
        for (int j = 0; j < 4; j++) {
            float o0 = __shfl_xor(acc[i][j][0], 1, 64);
            float o1 = __shfl_xor(acc[i][j][1], 1, 64);
            float o2 = __shfl_xor(acc[i][j][2], 1, 64);
            float o3 = __shfl_xor(acc[i][j][3], 1, 64);
            float m0 = odd ? acc[i][j][2] : acc[i][j][0];
            float m1 = odd ? acc[i][j][3] : acc[i][j][1];
            float p0 = odd ? o2 : o0;
            float p1 = odd ? o3 : o1;
            float h0 = odd ? p0 : m0, g0 = odd ? m0 : p0;
            float h1 = odd ? p1 : m1, g1 = odd ? m1 : p1;
            int row = i * 16 + q * 4 + odd * 2;
            int col = j * 8 + colL;
            EpW[(row    ) * 36 + col] = packCV(h0, g0);
            EpW[(row + 1) * 36 + col] = packCV(h1, g1);
        }
    }

    // ---- epilogue 2: quarter reduce (32 rows x 64 ch per thread-group) ----
    __syncthreads();                      // Ep fully written

    const int dl = tid & 63;              // channel 0..63 within block
    const int qt = tid >> 6;              // quarter 0..3 (rows qt*32 .. +31)
    const int wq = (qt >> 1) * 2 + (dl >> 5);
    const int rB = (qt & 1) * 32;
    const int cc_ = dl & 31;
    const unsigned int* src = EpBase + ((size_t)wq * 64 + rB) * 36 + cc_;
    {
        float C = 1.f, V = 0.f;
#pragma unroll 8
        for (int rr = 0; rr < 32; rr++) {
            union { unsigned int u; f16x2 h; } uu;
            uu.u = src[rr * 36];
            float cv_c = (float)uu.h[0], cv_v = (float)uu.h[1];
            V = fmaf(cv_c, V, cv_v);
            C *= cv_c;
        }
        scratch[(qt * 64 + dl) * 2 + 0] = C;
        scratch[(qt * 64 + dl) * 2 + 1] = V;
    }
    __syncthreads();

    // ---- epilogue 3 (wave 0 only): publish aggregate, then lookback ----
    // Relaxed agent-scope 8B atomic publish: the payload IS the data
    // (sentinel-validated); no fence (round-2's fence caused L2 inv: -35us).
    if (tid < 64) {
        float C0 = scratch[(0 * 64 + tid) * 2], V0 = scratch[(0 * 64 + tid) * 2 + 1];
        float C1 = scratch[(1 * 64 + tid) * 2], V1 = scratch[(1 * 64 + tid) * 2 + 1];
        float C2 = scratch[(2 * 64 + tid) * 2], V2 = scratch[(2 * 64 + tid) * 2 + 1];
        float C3 = scratch[(3 * 64 + tid) * 2], V3 = scratch[(3 * 64 + tid) * 2 + 1];
        float Cb = (C0 * C1) * (C2 * C3);
        float Vb = fmaf(C3, fmaf(C2, fmaf(C1, V0, V1), V2), V3);
        union { unsigned long long u; float f[2]; } pk;
        pk.f[0] = Cb; pk.f[1] = Vb;
        // UNCONDITIONAL publish before any wait -> no deadlock possible.
        __hip_atomic_store(&segAgg[(size_t)ord * 64 + tid], pk.u,
                           __ATOMIC_RELAXED, __HIP_MEMORY_SCOPE_AGENT);

        // aggregate-only lookback: fold predecessors t = 0..sIx-1 in order.
        float h = 0.f;
        const size_t chanB = (size_t)inner * 64 + tid;  // (eB*4+bat)*64+ch
#pragma unroll 1
        for (int t0 = 0; t0 < NCHAIN; t0 += 8) {
            if (t0 >= sIx) break;
            unsigned long long vb[8];
#pragma unroll
            for (int k = 0; k < 8; k++)
                vb[k] = (t0 + k < sIx)
                    ? __hip_atomic_load(&segAgg[(size_t)(t0 + k) * 4096 + chanB],
                                        __ATOMIC_RELAXED, __HIP_MEMORY_SCOPE_AGENT)
                    : 0x3f800000ull;    // identity (C=1, V=0)
#pragma unroll
            for (int k = 0; k < 8; k++) {
                if (t0 + k < sIx) {
                    while (vb[k] == SENT)
                        vb[k] = __hip_atomic_load(&segAgg[(size_t)(t0 + k) * 4096 + chanB],
                                                  __ATOMIC_RELAXED, __HIP_MEMORY_SCOPE_AGENT);
                }
            }
#pragma unroll
            for (int k = 0; k < 8; k++) {
                union { unsigned long long u; float f[2]; } qd; qd.u = vb[k];
                h = fmaf(qd.f[0], h, qd.f[1]);
            }
        }
        hpre[tid] = h;
    }
    __syncthreads();

    // ---- epilogue 4: apply h_t = c_t*h_{t-1} + v_t, write out (fp32, NT
    // stores: 64MB stream must not evict wb panels from per-XCD L2) ----
    {
        float h = hpre[dl];
        if (qt > 0) h = fmaf(scratch[(0 * 64 + dl) * 2], h, scratch[(0 * 64 + dl) * 2 + 1]);
        if (qt > 1) h = fmaf(scratch[(1 * 64 + dl) * 2], h, scratch[(1 * 64 + dl) * 2 + 1]);
        if (qt > 2) h = fmaf(scratch[(2 * 64 + dl) * 2], h, scratch[(2 * 64 + dl) * 2 + 1]);
        float* outp = out + (size_t)(mBase + qt * 32) * D_ + (eB * 64 + dl);
#pragma unroll 8
        for (int rr = 0; rr < 32; rr++) {
            union { unsigned int u; f16x2 hh; } uu;
            uu.u = src[rr * 36];
            h = fmaf((float)uu.hh[0], h, (float)uu.hh[1]);
            __builtin_nontemporal_store(h, outp + (size_t)rr * D_);
        }
    }
}

// ---------------- launch ----------------
extern "C" void kernel_launch(void* const* d_in, const int* in_sizes, int n_in,
                              void* d_out, int out_size, void* d_ws, size_t ws_size,
                              hipStream_t stream) {
    const float* x = (const float*)d_in[0];
    const float* wmat = (const float*)d_in[1];
    float* out = (float*)d_out;
    char* ws = (char*)d_ws;

    unsigned short* xb = (unsigned short*)(ws);                       // 32 MB @ 0
    unsigned short* wb = (unsigned short*)(ws + (32u << 20));         //  4 MB @ 32M
    unsigned long long* segAgg = (unsigned long long*)(ws + (36u << 20)); // 1 MB @ 36M

    cvt_xw<<<2368, 256, 0, stream>>>(x, xb, wmat, wb, segAgg);
    gemm_fused<<<2048, 256, 0, stream>>>(xb, wb, segAgg, out);
}

// Round 10
// 195.199 us; speedup vs baseline: 1.2283x; 1.0166x over previous
//
#include <hip/hip_runtime.h>
#include <stdint.h>

#define B_ 4
#define S_ 4096
#define D_ 1024
#define E_ 2048          // 2*D
#define K_ 1024
#define M_ (B_*S_)       // 16384
#define NCHAIN 16        // 256-row tiles per batch = chain length
#define SENT 0xFFFFFFFFFFFFFFFFull

typedef __bf16 bf16x8 __attribute__((ext_vector_type(8)));
typedef float  f32x4  __attribute__((ext_vector_type(4)));
typedef _Float16 f16x2 __attribute__((ext_vector_type(2)));

#define BM 256
#define BN 128
#define BK 32

__device__ __forceinline__ unsigned short f2bf(float f) {
    union { float f; unsigned int u; } x; x.f = f;
    unsigned int u = x.u;
    return (unsigned short)((u + 0x7fffu + ((u >> 16) & 1u)) >> 16);
}

__device__ __forceinline__ void gload16(const void* g, void* l) {
    __builtin_amdgcn_global_load_lds(
        (const __attribute__((address_space(1))) void*)(uintptr_t)g,
        (__attribute__((address_space(3))) void*)(uintptr_t)l,
        16, 0, 0);
}

// pack (c = sigmoid(-gate), v = sigmoid(gate)*g(hidden)) as half2 in a uint
__device__ __forceinline__ unsigned int packCV(float hid, float gat) {
    float e  = __expf(gat);
    float c  = __builtin_amdgcn_rcpf(1.f + e);          // sigmoid(-gate)
    float gg = (hid >= 0.f) ? (hid + 0.5f)
                            : __builtin_amdgcn_rcpf(1.f + __expf(-hid));
    float v  = (1.f - c) * gg;                           // sigmoid(gate)*g(hidden)
    union { f16x2 h; unsigned int u; } pk;
    pk.h[0] = (_Float16)c; pk.h[1] = (_Float16)v;
    return pk.u;
}

// ---------------- conversion + lookback-state init (grid-strided, 8x ILP) -----
// [0,2048): x -> bf16; [2048,2304): W interleave; [2304,2336): segAgg sentinels.
__global__ __launch_bounds__(256)
void cvt_xw(const float* __restrict__ x, unsigned short* __restrict__ xb,
            const float* __restrict__ w, unsigned short* __restrict__ wb,
            unsigned long long* __restrict__ segAgg) {
    const int b = blockIdx.x;
    const int t = threadIdx.x;
    if (b < 2048) {
        const float4* xp = (const float4*)x + (size_t)b * 2048 + t;
        ushort4*      op = (ushort4*)xb + (size_t)b * 2048 + t;
        float4 f[8];
#pragma unroll
        for (int k = 0; k < 8; k++) f[k] = xp[(size_t)k * 256];
#pragma unroll
        for (int k = 0; k < 8; k++) {
            ushort4 o;
            o.x = f2bf(f[k].x); o.y = f2bf(f[k].y);
            o.z = f2bf(f[k].z); o.w = f2bf(f[k].w);
            op[(size_t)k * 256] = o;
        }
    } else if (b < 2304) {
        const int base4 = (b - 2048) * 2048 + t;    // float4 index into [E_,K_]
        float4 f[8];
        const float* srcs[8];
#pragma unroll
        for (int k = 0; k < 8; k++) {
            int i = (base4 + k * 256) * 4;
            int r = i >> 10;
            int kk = i & 1023;
            int d = r >> 1, g = r & 1;
            srcs[k] = w + (size_t)(g * D_ + d) * K_ + kk;
        }
#pragma unroll
        for (int k = 0; k < 8; k++) f[k] = *(const float4*)srcs[k];
#pragma unroll
        for (int k = 0; k < 8; k++) {
            int i = (base4 + k * 256) * 4;
            ushort4 o;
            o.x = f2bf(f[k].x); o.y = f2bf(f[k].y);
            o.z = f2bf(f[k].z); o.w = f2bf(f[k].w);
            *(ushort4*)(wb + i) = o;
        }
    } else {
        // sentinel: 65536 u64 = 32 blocks * 256 threads * 8
        const size_t base = (size_t)(b - 2304) * 2048 + t;
#pragma unroll
        for (int k = 0; k < 8; k++) segAgg[base + (size_t)k * 256] = SENT;
    }
}

// one K-step: 12 frag reads -> 32 MFMAs (128x64 wave tile). B first (4 reads,
// 16 regs), then per-i A read + 4 MFMAs (limits live frag regs). No setprio
// (round-9: null/negative in this barrier-synced structure).
__device__ __forceinline__ void kstep(const unsigned short* Ab, const unsigned short* Bb,
                                      int waveM, int waveN, int mrow, int kgx,
                                      f32x4 acc[8][4]) {
    bf16x8 bfr[4];
#pragma unroll
    for (int j = 0; j < 4; j++)
        bfr[j] = *(const bf16x8*)(Bb + (size_t)(waveN + j * 16 + mrow) * BK + kgx);
#pragma unroll
    for (int i = 0; i < 8; i++) {
        bf16x8 af = *(const bf16x8*)(Ab + (size_t)(waveM + i * 16 + mrow) * BK + kgx);
#pragma unroll
        for (int j = 0; j < 4; j++)
            acc[i][j] = __builtin_amdgcn_mfma_f32_16x16x32_bf16(af, bfr[j], acc[i][j], 0, 0, 0);
    }
}

// ---------------- GEMM 256x128 + activation + in-block scan/apply -------------
// 4 waves x (128x64) acc[8][4]: LDS traffic 3GB total (vs 4.5GB at 64x64/wave).
// 3-buffer 2-deep pipeline, counted vmcnt(6) (6 gloads/stage); chunk-XOR bank
// swizzle (round 8: conflicts 8.4M -> 0). LDS: bufs 72KB overlaid post-loop by
// Ep 72KB; +scratch 2.25KB = 74.25KB -> 2 blocks/CU. VGPR ~acc128+frags: (256,2).
__global__ __launch_bounds__(256, 2)
void gemm_fused(const unsigned short* __restrict__ xb,
                const unsigned short* __restrict__ wb,
                unsigned long long* __restrict__ segAgg,
                float* __restrict__ out) {
    __shared__ __align__(16) char smem[76032];
    unsigned short* A0 = (unsigned short*)(smem);            // 16KB each
    unsigned short* A1 = (unsigned short*)(smem + 16384);
    unsigned short* A2 = (unsigned short*)(smem + 32768);
    unsigned short* B0 = (unsigned short*)(smem + 49152);    // 8KB each
    unsigned short* B1 = (unsigned short*)(smem + 57344);
    unsigned short* B2 = (unsigned short*)(smem + 65536);    // ends 73728
    unsigned int*   EpBase = (unsigned int*)(smem);          // [4][128][36]=72KB overlay
    float* scratch = (float*)(smem + 73728);                 // [4][64][2] = 2KB
    float* hpre    = (float*)(smem + 75776);                 // 64 floats

    // ord = s*64 + (eB*4 + bat): chain position s SLOWEST (lookback-safe).
    // XCD j (= ord%8) gets bat=j&3 + 8 eB panels of parity j>>2 (2MB wb/XCD).
    const int ord   = blockIdx.x;       // 0..1023
    const int inner = ord & 63;
    const int eB    = inner >> 2;       // 0..15
    const int bat   = inner & 3;        // 0..3
    const int sIx   = ord >> 6;         // 0..15 chain position within batch
    const int mB    = bat * NCHAIN + sIx;
    const int mBase = mB * BM;
    const int eBase = eB * BN;

    const int tid  = threadIdx.x;
    const int lane = tid & 63;
    const int w    = tid >> 6;
    const int waveM = (w >> 1) * 128;
    const int waveN = (w & 1) * 64;

    f32x4 acc[8][4] = {};

    // staging: thread tid covers (row = tid>>2 within each 64-row group, LDS
    // chunk c_l = tid&3); GLOBAL chunk swizzled c_g = c_l ^ ((row>>1)&3).
    // Row offsets are multiples of 64 -> same XOR for every stage call.
    const int row0 = tid >> 2, cu = tid & 3;
    const int cg   = cu ^ ((row0 >> 1) & 3);
    const unsigned short* aG0 = xb + (size_t)(mBase + row0) * K_ + cg * 8;
    const unsigned short* aG1 = aG0 + (size_t)64 * K_;
    const unsigned short* aG2 = aG0 + (size_t)128 * K_;
    const unsigned short* aG3 = aG0 + (size_t)192 * K_;
    const unsigned short* bG0 = wb + (size_t)(eBase + row0) * K_ + cg * 8;
    const unsigned short* bG1 = bG0 + (size_t)64 * K_;
    const int woff = w * 512;           // wave-uniform LDS base (shorts)

    const int mrow = lane & 15;
    const int kgx  = (((lane >> 4) ^ ((mrow >> 1) & 3))) * 8;

#define STAGE(Ab, Bb, kk) do { \
        gload16(aG0 + (kk), (Ab) + woff); \
        gload16(aG1 + (kk), (Ab) + 2048 + woff); \
        gload16(aG2 + (kk), (Ab) + 4096 + woff); \
        gload16(aG3 + (kk), (Ab) + 6144 + woff); \
        gload16(bG0 + (kk), (Bb) + woff); \
        gload16(bG1 + (kk), (Bb) + 2048 + woff); \
    } while (0)

    // ---- K-loop: 32 tiles, 2-deep prefetch, 6 loads/stage -> vmcnt(6)
    // steady state (oldest 6 = next tile landed; newest 6 in flight across
    // the barrier). lgkmcnt(0): own frag reads done before others overwrite.
#define STEP_MID(CA, CB, SA, SB, kks) do { \
        STAGE(SA, SB, (kks)); \
        __builtin_amdgcn_sched_barrier(0); \
        kstep(CA, CB, waveM, waveN, mrow, kgx, acc); \
        asm volatile("s_waitcnt vmcnt(6) lgkmcnt(0)" ::: "memory"); \
        __builtin_amdgcn_s_barrier(); \
    } while (0)

    STAGE(A0, B0, 0);
    STAGE(A1, B1, BK);
    asm volatile("s_waitcnt vmcnt(6)" ::: "memory");   // tile 0 (oldest 6) landed
    __builtin_amdgcn_s_barrier();

    for (int t = 0; t < 30; t += 3) {
        const int kk = t * BK;
        STEP_MID(A0, B0, A2, B2, kk + 2 * BK);   // compute t,   stage t+2
        STEP_MID(A1, B1, A0, B0, kk + 3 * BK);   // compute t+1, stage t+3
        STEP_MID(A2, B2, A1, B1, kk + 4 * BK);   // compute t+2, stage t+4
    }
    // tiles 30 (buf0) and 31 (buf1); drain to 0 at the tail.
    kstep(A0, B0, waveM, waveN, mrow, kgx, acc);
    asm volatile("s_waitcnt vmcnt(0) lgkmcnt(0)" ::: "memory");
    __builtin_amdgcn_s_barrier();
    kstep(A1, B1, waveM, waveN, mrow, kgx, acc);
    asm volatile("s_waitcnt lgkmcnt(0)" ::: "memory"); // all frag reads done
    __builtin_amdgcn_s_barrier();                      // before Ep overlay
#undef STEP_MID
#undef STAGE

    // ---- epilogue 1: activation + pack + LDS transpose (Ep overlays bufs).
    // Wave tile 128 rows x 64 e-cols -> EpW[128][36] (32 channel uints + pad).
    const int q    = lane >> 4;
    const int odd  = lane & 1;
    const int colL = (lane & 15) >> 1;            // 0..7
    unsigned int* EpW = EpBase + w * (128 * 36);

#pragma unroll
    for (int i = 0; i < 8; i++) {
#pragma unroll
        for (int j = 0; j < 4; j++) {
            float o0 = __shfl_xor(acc[i][j][0], 1, 64);
            float o1 = __shfl_xor(acc[i][j][1], 1, 64);
            float o2 = __shfl_xor(acc[i][j][2], 1, 64);
            float o3 = __shfl_xor(acc[i][j][3], 1, 64);
            float m0 = odd ? acc[i][j][2] : acc[i][j][0];
            float m1 = odd ? acc[i][j][3] : acc[i][j][1];
            float p0 = odd ? o2 : o0;
            float p1 = odd ? o3 : o1;
            float h0 = odd ? p0 : m0, g0 = odd ? m0 : p0;
            float h1 = odd ? p1 : m1, g1 = odd ? m1 : p1;
            int row = i * 16 + q * 4 + odd * 2;
            int col = j * 8 + colL;
            EpW[(row    ) * 36 + col] = packCV(h0, g0);
            EpW[(row + 1) * 36 + col] = packCV(h1, g1);
        }
    }

    // ---- epilogue 2: quarter reduce (64 rows x 64 ch per thread-group) ----
    __syncthreads();                      // Ep fully written

    const int dl = tid & 63;              // channel 0..63 within block
    const int qt = tid >> 6;              // quarter 0..3 (rows qt*64 .. +63)
    const int wq = (qt >> 1) * 2 + (dl >> 5);   // wave owning (row-half, ch-half)
    const int rB = (qt & 1) * 64;
    const int cc_ = dl & 31;
    const unsigned int* src = EpBase + ((size_t)wq * 128 + rB) * 36 + cc_;
    {
        float C = 1.f, V = 0.f;
#pragma unroll 8
        for (int rr = 0; rr < 64; rr++) {
            union { unsigned int u; f16x2 h; } uu;
            uu.u = src[rr * 36];
            float cv_c = (float)uu.h[0], cv_v = (float)uu.h[1];
            V = fmaf(cv_c, V, cv_v);
            C *= cv_c;
        }
        scratch[(qt * 64 + dl) * 2 + 0] = C;
        scratch[(qt * 64 + dl) * 2 + 1] = V;
    }
    __syncthreads();

    // ---- epilogue 3 (wave 0 only): publish aggregate, then lookback ----
    // Relaxed agent-scope 8B atomic publish: payload IS the data (sentinel-
    // validated); no fence (round-2: fence caused L2 inv, -35us).
    if (tid < 64) {
        float C0 = scratch[(0 * 64 + tid) * 2], V0 = scratch[(0 * 64 + tid) * 2 + 1];
        float C1 = scratch[(1 * 64 + tid) * 2], V1 = scratch[(1 * 64 + tid) * 2 + 1];
        float C2 = scratch[(2 * 64 + tid) * 2], V2 = scratch[(2 * 64 + tid) * 2 + 1];
        float C3 = scratch[(3 * 64 + tid) * 2], V3 = scratch[(3 * 64 + tid) * 2 + 1];
        float Cb = (C0 * C1) * (C2 * C3);
        float Vb = fmaf(C3, fmaf(C2, fmaf(C1, V0, V1), V2), V3);
        union { unsigned long long u; float f[2]; } pk;
        pk.f[0] = Cb; pk.f[1] = Vb;
        // UNCONDITIONAL publish before any wait -> no deadlock possible.
        __hip_atomic_store(&segAgg[(size_t)ord * 64 + tid], pk.u,
                           __ATOMIC_RELAXED, __HIP_MEMORY_SCOPE_AGENT);

        // aggregate-only lookback: fold predecessors t = 0..sIx-1 in order.
        float h = 0.f;
        const size_t chanB = (size_t)inner * 64 + tid;  // (eB*4+bat)*64+ch
#pragma unroll 1
        for (int t0 = 0; t0 < NCHAIN; t0 += 8) {
            if (t0 >= sIx) break;
            unsigned long long vb[8];
#pragma unroll
            for (int k = 0; k < 8; k++)
                vb[k] = (t0 + k < sIx)
                    ? __hip_atomic_load(&segAgg[(size_t)(t0 + k) * 4096 + chanB],
                                        __ATOMIC_RELAXED, __HIP_MEMORY_SCOPE_AGENT)
                    : 0x3f800000ull;    // identity (C=1, V=0)
#pragma unroll
            for (int k = 0; k < 8; k++) {
                if (t0 + k < sIx) {
                    while (vb[k] == SENT)
                        vb[k] = __hip_atomic_load(&segAgg[(size_t)(t0 + k) * 4096 + chanB],
                                                  __ATOMIC_RELAXED, __HIP_MEMORY_SCOPE_AGENT);
                }
            }
#pragma unroll
            for (int k = 0; k < 8; k++) {
                union { unsigned long long u; float f[2]; } qd; qd.u = vb[k];
                h = fmaf(qd.f[0], h, qd.f[1]);
            }
        }
        hpre[tid] = h;
    }
    __syncthreads();

    // ---- epilogue 4: apply h_t = c_t*h_{t-1} + v_t, write out (fp32, NT
    // stores: 64MB stream must not evict wb panels from per-XCD L2) ----
    {
        float h = hpre[dl];
        if (qt > 0) h = fmaf(scratch[(0 * 64 + dl) * 2], h, scratch[(0 * 64 + dl) * 2 + 1]);
        if (qt > 1) h = fmaf(scratch[(1 * 64 + dl) * 2], h, scratch[(1 * 64 + dl) * 2 + 1]);
        if (qt > 2) h = fmaf(scratch[(2 * 64 + dl) * 2], h, scratch[(2 * 64 + dl) * 2 + 1]);
        float* outp = out + (size_t)(mBase + qt * 64) * D_ + (eB * 64 + dl);
#pragma unroll 8
        for (int rr = 0; rr < 64; rr++) {
            union { unsigned int u; f16x2 hh; } uu;
            uu.u = src[rr * 36];
            h = fmaf((float)uu.hh[0], h, (float)uu.hh[1]);
            __builtin_nontemporal_store(h, outp + (size_t)rr * D_);
        }
    }
}

// ---------------- launch ----------------
extern "C" void kernel_launch(void* const* d_in, const int* in_sizes, int n_in,
                              void* d_out, int out_size, void* d_ws, size_t ws_size,
                              hipStream_t stream) {
    const float* x = (const float*)d_in[0];
    const float* wmat = (const float*)d_in[1];
    float* out = (float*)d_out;
    char* ws = (char*)d_ws;

    unsigned short* xb = (unsigned short*)(ws);                       // 32 MB @ 0
    unsigned short* wb = (unsigned short*)(ws + (32u << 20));         //  4 MB @ 32M
    unsigned long long* segAgg = (unsigned long long*)(ws + (36u << 20)); // 512KB @ 36M

    cvt_xw<<<2336, 256, 0, stream>>>(x, xb, wmat, wb, segAgg);
    gemm_fused<<<1024, 256, 0, stream>>>(xb, wb, segAgg, out);
}